// Round 6
// baseline (506.278 us; speedup 1.0000x reference)
//
#include <hip/hip_runtime.h>
#include <cstdint>
#include <cstddef>

#define NPTS 16384
#define KSEL 4096
#define HIDDEN 128
#define NHEADS 8
#define DHEAD 16
#define OUTD 256
#define NSLICE 4   // k/q slices for attn partials
#define FCAP 131072

typedef __attribute__((ext_vector_type(8))) short bf16x8;
typedef __attribute__((ext_vector_type(4))) float f32x4;

#if defined(__has_builtin)
#if __has_builtin(__builtin_amdgcn_exp2f)
#define E2(x) __builtin_amdgcn_exp2f(x)
#endif
#endif
#ifndef E2
#define E2(x) exp2f(x)
#endif

// ---- workspace layout (bytes) ----
constexpr size_t OFF_PA    = 1024;                         // NPTS*16 bf16 (A-side packed, -2x)
constexpr size_t OFF_PB    = OFF_PA  + (size_t)NPTS*32;    // NPTS*16 bf16 (B-side packed)
constexpr size_t OFF_SQ    = OFF_PB  + (size_t)NPTS*32;
constexpr size_t OFF_DL    = OFF_SQ  + (size_t)NPTS*4;
constexpr size_t OFF_CNT   = OFF_DL  + (size_t)NPTS*4;     // int (memset 0)
constexpr size_t OFF_NFLAG = OFF_CNT + (size_t)NPTS*4;     // uint (memset 0, padded 1KB)
constexpr size_t OFF_FLG   = OFF_NFLAG + 1024;             // FCAP uints
constexpr size_t OFF_SEL   = OFF_FLG + (size_t)FCAP*4;     // KSEL int
constexpr size_t SZ_PK     = (size_t)NHEADS*KSEL*32*2;     // 2 MB packed [hi16|lo16] bf16
constexpr size_t OFF_QPK   = OFF_SEL + (size_t)KSEL*4;
constexpr size_t OFF_KPK   = OFF_QPK + SZ_PK;
constexpr size_t OFF_V     = OFF_KPK + SZ_PK;                      // KSEL*128 f32
constexpr size_t OFF_LP    = OFF_V  + (size_t)KSEL*HIDDEN*4;       // 8*4096*4 f32 partial l
constexpr size_t OFF_RL    = OFF_LP + (size_t)NHEADS*KSEL*NSLICE*4; // 8*4096 f32 1/l
constexpr size_t OFF_WP    = OFF_RL + (size_t)NHEADS*KSEL*4;        // 8*4096*4 f32 partial w
constexpr size_t OFF_PAV   = OFF_WP + (size_t)NHEADS*KSEL*NSLICE*4; // 128 f32

__device__ __forceinline__ unsigned short f2bf(float f) {
    union { float f; unsigned u; } v; v.f = f;
    unsigned r = v.u + 0x7fffu + ((v.u >> 16) & 1u);
    return (unsigned short)(r >> 16);
}
__device__ __forceinline__ float bf2f(unsigned short h) {
    union { unsigned u; float f; } v; v.u = ((unsigned)h) << 16;
    return v.f;
}

// ---- 1. prep: ligand center, sq, d_lig, packed hi/lo coords for MFMA d2 ----
__global__ void __launch_bounds__(256) k_prep(const float* __restrict__ pos, const float* __restrict__ lig, int M,
                       unsigned short* __restrict__ pa, unsigned short* __restrict__ pb,
                       float* __restrict__ sq, float* __restrict__ dl) {
    __shared__ float ls[128];
    __shared__ float ctr[3];
    int tid = threadIdx.x;
    for (int i = tid; i < 3 * M; i += 256) ls[i] = lig[i];
    __syncthreads();
    if (tid < 3) {
        float s = 0.f;
        for (int i = 0; i < M; i++) s += ls[i * 3 + tid];
        ctr[tid] = s / (float)M;
    }
    __syncthreads();
    int i = blockIdx.x * 256 + tid;
    float x = pos[i*3+0], y = pos[i*3+1], z = pos[i*3+2];
    sq[i] = (x*x + y*y) + z*z;
    float dx = x - ctr[0], dy = y - ctr[1], dz = z - ctr[2];
    dl[i] = sqrtf((dx*dx + dy*dy) + dz*dz);
    // hi/lo split per coord
    unsigned short xh = f2bf(x); float xr = bf2f(xh); float xl = x - xr;
    unsigned short yh = f2bf(y); float yr = bf2f(yh); float yl = y - yr;
    unsigned short zh = f2bf(z); float zr = bf2f(zh); float zl = z - zr;
    unsigned short xlb = f2bf(xl), ylb = f2bf(yl), zlb = f2bf(zl);
    unsigned short xhA = f2bf(-2.f*xr), xlA = f2bf(-2.f*xl);
    unsigned short yhA = f2bf(-2.f*yr), ylA = f2bf(-2.f*yl);
    unsigned short zhA = f2bf(-2.f*zr), zlA = f2bf(-2.f*zl);
    union { unsigned short s[16]; float4 f[2]; } A, B;
    #pragma unroll
    for (int t = 0; t < 16; t++) { A.s[t] = 0; B.s[t] = 0; }
    // k-slot products (A from point i scaled by -2, B from point j):
    // 0: hh  1: h*lo_j  2: lo_i*h  (per coord x,y,z)  9-11: lo_i*lo_j compensation
    A.s[0]=xhA; A.s[1]=xhA; A.s[2]=xlA;
    A.s[3]=yhA; A.s[4]=yhA; A.s[5]=ylA;
    A.s[6]=zhA; A.s[7]=zhA; A.s[8]=zlA;
    A.s[9]=xlA; A.s[10]=ylA; A.s[11]=zlA;
    B.s[0]=xh;  B.s[1]=xlb;  B.s[2]=xh;
    B.s[3]=yh;  B.s[4]=ylb;  B.s[5]=yh;
    B.s[6]=zh;  B.s[7]=zlb;  B.s[8]=zh;
    B.s[9]=xlb; B.s[10]=ylb; B.s[11]=zlb;
    float4* pad = (float4*)(pa + (size_t)i * 16);
    pad[0] = A.f[0]; pad[1] = A.f[1];
    float4* pbd = (float4*)(pb + (size_t)i * 16);
    pbd[0] = B.f[0]; pbd[1] = B.f[1];
}

// ---- 2. neighbor counts via MFMA: c = (si+sj) + A.B ~= d2; exact near boundary via fixup ----
// grid (igrp=256, jsplit=4), block 256 = 4 waves x 16 i-rows
__global__ void __launch_bounds__(256) k_neighbor(
        const unsigned short* __restrict__ pa, const unsigned short* __restrict__ pb,
        const float* __restrict__ sq, int* __restrict__ cnt,
        unsigned int* __restrict__ flg, unsigned int* __restrict__ nflag) {
    __shared__ unsigned short bs[256 * 24];   // 48B row stride: 16B-aligned, 2-way aliasing only
    __shared__ float sjs[256];
    int tid = threadIdx.x;
    int lane = tid & 63, w = tid >> 6;
    int n = lane & 15, g = lane >> 4;
    int i0 = blockIdx.x * 64 + w * 16;
    bf16x8 afrag = {0,0,0,0,0,0,0,0};
    if (g < 2) afrag = *(const bf16x8*)(pa + (size_t)(i0 + n) * 16 + g * 8);
    int irow = i0 + g * 4;
    float si0 = sq[irow+0], si1 = sq[irow+1], si2 = sq[irow+2], si3 = sq[irow+3];
    int boff = (g < 2) ? g * 8 : 0;   // g>=2: read valid data, annihilated by A=0
    int jb0 = blockIdx.y * 4096;
    int c0 = 0, c1 = 0, c2 = 0, c3 = 0;
    for (int ch = 0; ch < 16; ch++) {
        __syncthreads();
        int jb = jb0 + ch * 256;
        {
            const float4* src = (const float4*)(pb + (size_t)(jb + tid) * 16);
            float4 v0 = src[0], v1 = src[1];
            float4* dst = (float4*)&bs[tid * 24];
            dst[0] = v0; dst[1] = v1;
            sjs[tid] = sq[jb + tid];
        }
        __syncthreads();
        #pragma unroll 4
        for (int t = 0; t < 16; t++) {
            int jj = t * 16 + n;
            bf16x8 bfrag = *(const bf16x8*)&bs[jj * 24 + boff];
            float sj = sjs[jj];
            float s0 = si0 + sj, s1 = si1 + sj, s2 = si2 + sj, s3 = si3 + sj;
            f32x4 c; c[0] = s0; c[1] = s1; c[2] = s2; c[3] = s3;
            c = __builtin_amdgcn_mfma_f32_16x16x32_bf16(afrag, bfrag, c, 0, 0, 0);
            // tau = 3e-4*(si+sj) + 0.01 >> bf16-split error bound (~3e-5*(si+sj))
            float t0 = fmaf(s0, 3.0e-4f, 0.01f), t1 = fmaf(s1, 3.0e-4f, 0.01f);
            float t2 = fmaf(s2, 3.0e-4f, 0.01f), t3 = fmaf(s3, 3.0e-4f, 0.01f);
            float d0 = c[0] - 9.0f, d1 = c[1] - 9.0f, d2_ = c[2] - 9.0f, d3 = c[3] - 9.0f;
            c0 += (d0 < -t0); c1 += (d1 < -t1); c2 += (d2_ < -t2); c3 += (d3 < -t3);
            int j = jb + jj;
            if (fabsf(d0) < t0) { unsigned idx = atomicAdd(nflag, 1u); if (idx < FCAP) flg[idx] = ((unsigned)(irow+0) << 14) | (unsigned)j; }
            if (fabsf(d1) < t1) { unsigned idx = atomicAdd(nflag, 1u); if (idx < FCAP) flg[idx] = ((unsigned)(irow+1) << 14) | (unsigned)j; }
            if (fabsf(d2_) < t2) { unsigned idx = atomicAdd(nflag, 1u); if (idx < FCAP) flg[idx] = ((unsigned)(irow+2) << 14) | (unsigned)j; }
            if (fabsf(d3) < t3) { unsigned idx = atomicAdd(nflag, 1u); if (idx < FCAP) flg[idx] = ((unsigned)(irow+3) << 14) | (unsigned)j; }
        }
    }
    #pragma unroll
    for (int m = 1; m < 16; m <<= 1) {
        c0 += __shfl_xor(c0, m); c1 += __shfl_xor(c1, m);
        c2 += __shfl_xor(c2, m); c3 += __shfl_xor(c3, m);
    }
    if (n == 0) {
        atomicAdd(&cnt[irow+0], c0);
        atomicAdd(&cnt[irow+1], c1);
        atomicAdd(&cnt[irow+2], c2);
        atomicAdd(&cnt[irow+3], c3);
    }
}

// ---- 2b. resolve boundary-window pairs with the exact fp32 formula (matches R1-R3) ----
__global__ void __launch_bounds__(256) k_fixup(const float* __restrict__ pos, const float* __restrict__ sq,
        const unsigned int* __restrict__ flg, const unsigned int* __restrict__ nflag,
        int* __restrict__ cnt) {
    int nf = (int)*nflag; if (nf > FCAP) nf = FCAP;
    for (int idx = blockIdx.x * 256 + threadIdx.x; idx < nf; idx += gridDim.x * 256) {
        unsigned pr = flg[idx];
        int i = (int)(pr >> 14), j = (int)(pr & 16383u);
        float xi = pos[i*3+0], yi = pos[i*3+1], zi = pos[i*3+2];
        float xj = pos[j*3+0], yj = pos[j*3+1], zj = pos[j*3+2];
        float dot = fmaf(xi, xj, fmaf(yi, yj, zi * zj));
        float d2 = (sq[i] + sq[j]) - 2.0f * dot;
        if (d2 < 9.0f) atomicAdd(&cnt[i], 1);
    }
}

// ---- 3. scores (fused) + exact top-KSEL radix select (parallel suffix scan) ----
__global__ void __launch_bounds__(1024) k_select(const float* __restrict__ dl, const int* __restrict__ cnt,
                                                 int* __restrict__ sel) {
    __shared__ unsigned int sk[NPTS];
    __shared__ int hist[256];
    __shared__ int scan2[256];
    __shared__ unsigned int s_prefix;
    __shared__ int s_rem, s_eqtot, s_nout, s_digit, s_cgt;
    int tid = threadIdx.x;
    for (int i = tid; i < NPTS; i += 1024) {
        float score = 1.0f / (1.0f + dl[i] / 5.0f) + 0.5f * (1.0f / (float)cnt[i]);
        unsigned int u = __float_as_uint(score);
        sk[i] = u ^ ((u & 0x80000000u) ? 0xFFFFFFFFu : 0x80000000u);
    }
    if (tid == 0) { s_prefix = 0; s_rem = KSEL; s_nout = 0; s_eqtot = 0; }
    __syncthreads();
    for (int p = 0; p < 4; p++) {
        int sh = 24 - 8 * p;
        if (tid < 256) hist[tid] = 0;
        __syncthreads();
        unsigned int pref = s_prefix;
        int shp = (p == 0) ? 0 : (32 - 8 * p);
        for (int i = tid; i < NPTS; i += 1024) {
            unsigned int key = sk[i];
            bool m = (p == 0) || ((key >> shp) == pref);
            if (m) atomicAdd(&hist[(key >> sh) & 255], 1);
        }
        __syncthreads();
        if (tid < 256) scan2[tid] = hist[tid];
        __syncthreads();
        for (int off = 1; off < 256; off <<= 1) {
            int v = 0;
            if (tid < 256) { v = scan2[tid]; if (tid + off < 256) v += scan2[tid + off]; }
            __syncthreads();
            if (tid < 256) scan2[tid] = v;
            __syncthreads();
        }
        int rem = s_rem;
        if (tid < 256) {
            int hi = scan2[tid];          // sum_{d' >= tid}
            int lo = hi - hist[tid];      // sum_{d' > tid}
            if (hi >= rem && lo < rem) { s_digit = tid; s_cgt = lo; }
        }
        __syncthreads();
        if (tid == 0) {
            s_prefix = (s_prefix << 8) | (unsigned int)s_digit;
            s_rem = rem - s_cgt;
            if (p == 3) s_eqtot = hist[s_digit];
        }
        __syncthreads();
    }
    unsigned int T = s_prefix;
    int need_eq = s_rem;
    for (int i = tid; i < NPTS; i += 1024)
        if (sk[i] > T) sel[atomicAdd(&s_nout, 1)] = i;
    __syncthreads();
    if (s_eqtot == need_eq) {
        for (int i = tid; i < NPTS; i += 1024)
            if (sk[i] == T) sel[atomicAdd(&s_nout, 1)] = i;
    } else {
        for (int i = tid; i < NPTS; i += 1024) {
            if (sk[i] == T) {
                int rank = 0;
                for (int j = 0; j < i; j++) rank += (sk[j] == T);
                if (rank < need_eq) sel[atomicAdd(&s_nout, 1)] = i;
            }
        }
    }
}

// ---- 4. gather + node embed + QKV projections; Q/K -> packed bf16 [hi16|lo16] rows ----
__device__ __forceinline__ void proj8(const float hs[8][HIDDEN], const float* __restrict__ W,
                                      float b, int d, float* acc) {
    #pragma unroll
    for (int r = 0; r < 8; r++) acc[r] = b;
    for (int c = 0; c < HIDDEN; c += 4) {
        float w0 = W[(c+0)*HIDDEN+d], w1 = W[(c+1)*HIDDEN+d], w2 = W[(c+2)*HIDDEN+d], w3 = W[(c+3)*HIDDEN+d];
        #pragma unroll
        for (int r = 0; r < 8; r++) {
            float4 h4 = *(const float4*)&hs[r][c];
            float a = acc[r];
            a = fmaf(h4.x, w0, a); a = fmaf(h4.y, w1, a); a = fmaf(h4.z, w2, a); a = fmaf(h4.w, w3, a);
            acc[r] = a;
        }
    }
}

__global__ void __launch_bounds__(128) k_qkv(const float* __restrict__ x, const int* __restrict__ sel,
        const float* __restrict__ Wn, const float* __restrict__ bn,
        const float* __restrict__ Wq, const float* __restrict__ bq,
        const float* __restrict__ Wk, const float* __restrict__ bk,
        const float* __restrict__ Wv, const float* __restrict__ bv,
        unsigned short* __restrict__ qpk, unsigned short* __restrict__ kpk,
        float* __restrict__ vg) {
    __shared__ float xs[8][8];
    __shared__ __align__(16) float hs[8][HIDDEN];
    int d = threadIdx.x;
    int r0 = blockIdx.x * 8;
    if (d < 64) { int rr = d >> 3, cc = d & 7; xs[rr][cc] = x[(size_t)sel[r0 + rr] * 8 + cc]; }
    __syncthreads();
    {
        float wn[8];
        #pragma unroll
        for (int c = 0; c < 8; c++) wn[c] = Wn[c * HIDDEN + d];
        float b = bn[d];
        #pragma unroll
        for (int r = 0; r < 8; r++) {
            float a = b;
            #pragma unroll
            for (int c = 0; c < 8; c++) a = fmaf(xs[r][c], wn[c], a);
            hs[r][d] = a;
        }
    }
    __syncthreads();
    int hh = d >> 4, dd = d & 15;
    float acc[8];
    // Q (pre-scaled by log2(e)/4, split hi/lo)
    proj8(hs, Wq, bq[d], d, acc);
    #pragma unroll
    for (int r = 0; r < 8; r++) {
        float val = acc[r] * 0.36067376022224085f;
        unsigned short hi = f2bf(val);
        unsigned short lo = f2bf(val - bf2f(hi));
        size_t idx = ((size_t)(hh * KSEL) + r0 + r) * 32 + dd;
        qpk[idx] = hi; qpk[idx + 16] = lo;
    }
    // K
    proj8(hs, Wk, bk[d], d, acc);
    #pragma unroll
    for (int r = 0; r < 8; r++) {
        float val = acc[r];
        unsigned short hi = f2bf(val);
        unsigned short lo = f2bf(val - bf2f(hi));
        size_t idx = ((size_t)(hh * KSEL) + r0 + r) * 32 + dd;
        kpk[idx] = hi; kpk[idx + 16] = lo;
    }
    // V (fp32, row-major [q][128])
    proj8(hs, Wv, bv[d], d, acc);
    #pragma unroll
    for (int r = 0; r < 8; r++) vg[(size_t)(r0+r)*HIDDEN + d] = acc[r];
}

// ---- 5. phase 1: row sums l_q via MFMA; chunked LDS (256 rows, 80B stride) ----
__global__ void __launch_bounds__(256) k_attn_l(
        const unsigned short* __restrict__ qpk, const unsigned short* __restrict__ kpk,
        float* __restrict__ lp) {
    __shared__ unsigned short smem[256 * 40];
    int tid = threadIdx.x;
    int ks = blockIdx.x, yg = blockIdx.y, h = blockIdx.z;
    size_t hb = (size_t)h * KSEL;
    int lane = tid & 63, w = tid >> 6;
    int n = lane & 15, g = lane >> 4;
    int q0w = yg * 64 + w * 16;
    bf16x8 afrag = *(const bf16x8*)(qpk + (hb + q0w + n) * 32 + g * 8); // A=[Qh|Ql]
    float l0 = 0.f, l1 = 0.f, l2 = 0.f, l3 = 0.f;
    int b1off = (g & 1) * 8;
    int b2off = 16 + g * 8;
    for (int kc = 0; kc < 4; kc++) {
        __syncthreads();
        {
            int krow = ks * 1024 + kc * 256 + tid;
            const float4* src = (const float4*)(kpk + (hb + krow) * 32);
            float4 a0 = src[0], a1 = src[1], a2 = src[2], a3 = src[3];
            float4* dst = (float4*)&smem[tid * 40];
            dst[0] = a0; dst[1] = a1; dst[2] = a2; dst[3] = a3;
        }
        __syncthreads();
        #pragma unroll 4
        for (int t = 0; t < 16; t++) {
            const unsigned short* rowp = &smem[(t * 16 + n) * 40];
            bf16x8 b1 = *(const bf16x8*)(rowp + b1off);            // [Kh|Kh]
            bf16x8 b2 = {0,0,0,0,0,0,0,0};                          // [Kl|0]
            if (g < 2) b2 = *(const bf16x8*)(rowp + b2off);
            f32x4 c = {0.f, 0.f, 0.f, 0.f};
            c = __builtin_amdgcn_mfma_f32_16x16x32_bf16(afrag, b1, c, 0, 0, 0);
            c = __builtin_amdgcn_mfma_f32_16x16x32_bf16(afrag, b2, c, 0, 0, 0);
            l0 += E2(c[0]); l1 += E2(c[1]); l2 += E2(c[2]); l3 += E2(c[3]);
        }
    }
    #pragma unroll
    for (int m = 1; m < 16; m <<= 1) {
        l0 += __shfl_xor(l0, m); l1 += __shfl_xor(l1, m);
        l2 += __shfl_xor(l2, m); l3 += __shfl_xor(l3, m);
    }
    if (n == 0) {
        size_t base = (hb + q0w + g * 4) * NSLICE + ks;
        lp[base]            = l0; lp[base + NSLICE]     = l1;
        lp[base + 2*NSLICE] = l2; lp[base + 3*NSLICE]   = l3;
    }
}

// ---- 6. combine l partials -> 1/l ----
__global__ void k_rl(const float* __restrict__ lp, float* __restrict__ rl) {
    int i = blockIdx.x * 256 + threadIdx.x;
    float4 p = ((const float4*)lp)[i];
    rl[i] = 1.0f / ((p.x + p.y) + (p.z + p.w));
}

// ---- 7. phase 2: column weights w_j = sum_q exp(s)/l_q (A = K-row [Kh|Kl]) ----
__global__ void __launch_bounds__(256) k_attn_w(
        const unsigned short* __restrict__ qpk, const unsigned short* __restrict__ kpk,
        const float* __restrict__ rl, float* __restrict__ wp) {
    __shared__ unsigned short smem[256 * 40];
    __shared__ float rls[256];
    int tid = threadIdx.x;
    int qs = blockIdx.x, yg = blockIdx.y, h = blockIdx.z;
    size_t hb = (size_t)h * KSEL;
    int lane = tid & 63, w = tid >> 6;
    int n = lane & 15, g = lane >> 4;
    int j0w = yg * 64 + w * 16;
    bf16x8 afrag = *(const bf16x8*)(kpk + (hb + j0w + n) * 32 + g * 8); // A=[Kh|Kl]
    float w0 = 0.f, w1 = 0.f, w2 = 0.f, w3 = 0.f;
    int b1off = (g & 1) * 8;
    int b2off = 16 + g * 8;
    for (int qc = 0; qc < 4; qc++) {
        __syncthreads();
        {
            int qrow = qs * 1024 + qc * 256 + tid;
            const float4* src = (const float4*)(qpk + (hb + qrow) * 32);
            float4 a0 = src[0], a1 = src[1], a2 = src[2], a3 = src[3];
            float4* dst = (float4*)&smem[tid * 40];
            dst[0] = a0; dst[1] = a1; dst[2] = a2; dst[3] = a3;
            rls[tid] = rl[hb + qrow];
        }
        __syncthreads();
        #pragma unroll 4
        for (int t = 0; t < 16; t++) {
            const unsigned short* rowp = &smem[(t * 16 + n) * 40];
            bf16x8 b1 = *(const bf16x8*)(rowp + b1off);            // [Qh|Qh]
            bf16x8 b2 = {0,0,0,0,0,0,0,0};                          // [Ql|0]
            if (g < 2) b2 = *(const bf16x8*)(rowp + b2off);
            f32x4 c = {0.f, 0.f, 0.f, 0.f};
            c = __builtin_amdgcn_mfma_f32_16x16x32_bf16(afrag, b1, c, 0, 0, 0);
            c = __builtin_amdgcn_mfma_f32_16x16x32_bf16(afrag, b2, c, 0, 0, 0);
            float rv = rls[t * 16 + n];
            w0 = fmaf(E2(c[0]), rv, w0); w1 = fmaf(E2(c[1]), rv, w1);
            w2 = fmaf(E2(c[2]), rv, w2); w3 = fmaf(E2(c[3]), rv, w3);
        }
    }
    #pragma unroll
    for (int m = 1; m < 16; m <<= 1) {
        w0 += __shfl_xor(w0, m); w1 += __shfl_xor(w1, m);
        w2 += __shfl_xor(w2, m); w3 += __shfl_xor(w3, m);
    }
    if (n == 0) {
        size_t base = (hb + j0w + g * 4) * NSLICE + qs;
        wp[base]            = w0; wp[base + NSLICE]     = w1;
        wp[base + 2*NSLICE] = w2; wp[base + 3*NSLICE]   = w3;
    }
}

// ---- 8. pooled_av[d] += (1/K) sum_j w[h(d)][j] * v[j][d] ----
__global__ void __launch_bounds__(256) k_colsum(const float* __restrict__ wp, const float* __restrict__ vg,
                                                float* __restrict__ pav) {
    __shared__ float wl[NHEADS][128];
    __shared__ float red[128];
    int tid = threadIdx.x;
    int jb = blockIdx.x * 128;
    for (int i = tid; i < NHEADS * 128; i += 256) {
        int h = i >> 7, jl = i & 127;
        float4 p = ((const float4*)wp)[(size_t)h * KSEL + jb + jl];
        wl[h][jl] = (p.x + p.y) + (p.z + p.w);
    }
    __syncthreads();
    int d = tid & 127, g = tid >> 7;
    int h = d >> 4;
    float acc = 0.f;
    for (int jl = g * 64; jl < g * 64 + 64; jl++)
        acc = fmaf(wl[h][jl], vg[(size_t)(jb + jl) * HIDDEN + d], acc);
    if (g == 1) red[d] = acc;
    __syncthreads();
    if (g == 0) atomicAdd(&pav[d], (acc + red[d]) * (1.0f / (float)KSEL));
}

// ---- 9. out-proj + pool MLP ----
__global__ void __launch_bounds__(256) k_final(const float* __restrict__ pav,
        const float* __restrict__ Wo, const float* __restrict__ bo,
        const float* __restrict__ W1, const float* __restrict__ b1,
        const float* __restrict__ W2, const float* __restrict__ b2,
        float* __restrict__ out) {
    __shared__ float sp[HIDDEN];
    __shared__ float st[OUTD];
    int t = threadIdx.x;
    if (t < HIDDEN) {
        float a = bo[t];
        for (int c = 0; c < HIDDEN; c++) a = fmaf(pav[c], Wo[c * HIDDEN + t], a);
        sp[t] = a;
    }
    __syncthreads();
    {
        float a = b1[t];
        for (int c = 0; c < HIDDEN; c++) a = fmaf(sp[c], W1[c * OUTD + t], a);
        st[t] = fmaxf(a, 0.f);
    }
    __syncthreads();
    {
        float o = b2[t];
        for (int c = 0; c < OUTD; c++) o = fmaf(st[c], W2[c * OUTD + t], o);
        out[t] = o;
    }
}

extern "C" void kernel_launch(void* const* d_in, const int* in_sizes, int n_in,
                              void* d_out, int out_size, void* d_ws, size_t ws_size,
                              hipStream_t stream) {
    (void)n_in; (void)out_size; (void)ws_size;
    const float* x   = (const float*)d_in[0];
    const float* pos = (const float*)d_in[1];
    const float* lig = (const float*)d_in[2];
    const float* Wn  = (const float*)d_in[3];
    const float* bn  = (const float*)d_in[4];
    const float* Wq  = (const float*)d_in[5];
    const float* bq  = (const float*)d_in[6];
    const float* Wk  = (const float*)d_in[7];
    const float* bk  = (const float*)d_in[8];
    const float* Wv  = (const float*)d_in[9];
    const float* bv  = (const float*)d_in[10];
    const float* Wo  = (const float*)d_in[11];
    const float* bo  = (const float*)d_in[12];
    const float* W1  = (const float*)d_in[13];
    const float* b1  = (const float*)d_in[14];
    const float* W2  = (const float*)d_in[15];
    const float* b2  = (const float*)d_in[16];
    int M = in_sizes[2] / 3;

    char* ws = (char*)d_ws;
    unsigned short* pa  = (unsigned short*)(ws + OFF_PA);
    unsigned short* pb  = (unsigned short*)(ws + OFF_PB);
    float*          sq  = (float*)(ws + OFF_SQ);
    float*          dl  = (float*)(ws + OFF_DL);
    int*            cnt = (int*)  (ws + OFF_CNT);
    unsigned int*   nfl = (unsigned int*)(ws + OFF_NFLAG);
    unsigned int*   flg = (unsigned int*)(ws + OFF_FLG);
    int*            sel = (int*)  (ws + OFF_SEL);
    unsigned short* qpk = (unsigned short*)(ws + OFF_QPK);
    unsigned short* kpk = (unsigned short*)(ws + OFF_KPK);
    float*          vg  = (float*)(ws + OFF_V);
    float*          lp  = (float*)(ws + OFF_LP);
    float*          rl  = (float*)(ws + OFF_RL);
    float*          wp  = (float*)(ws + OFF_WP);
    float*          pav = (float*)(ws + OFF_PAV);

    hipMemsetAsync(ws + OFF_CNT, 0, (size_t)NPTS * 4 + 1024, stream);  // cnt + nflag
    hipMemsetAsync(ws + OFF_PAV, 0, (size_t)HIDDEN * 4, stream);

    hipLaunchKernelGGL(k_prep,     dim3(64),       dim3(256),  0, stream, pos, lig, M, pa, pb, sq, dl);
    hipLaunchKernelGGL(k_neighbor, dim3(256, 4),   dim3(256),  0, stream, pa, pb, sq, cnt, flg, nfl);
    hipLaunchKernelGGL(k_fixup,    dim3(32),       dim3(256),  0, stream, pos, sq, flg, nfl, cnt);
    hipLaunchKernelGGL(k_select,   dim3(1),        dim3(1024), 0, stream, dl, cnt, sel);
    hipLaunchKernelGGL(k_qkv,      dim3(KSEL/8),   dim3(128),  0, stream, x, sel, Wn, bn, Wq, bq, Wk, bk, Wv, bv, qpk, kpk, vg);
    hipLaunchKernelGGL(k_attn_l,   dim3(4, 64, 8), dim3(256),  0, stream, qpk, kpk, lp);
    hipLaunchKernelGGL(k_rl,       dim3(NHEADS*KSEL/256), dim3(256), 0, stream, lp, rl);
    hipLaunchKernelGGL(k_attn_w,   dim3(4, 64, 8), dim3(256),  0, stream, qpk, kpk, rl, wp);
    hipLaunchKernelGGL(k_colsum,   dim3(32),       dim3(256),  0, stream, wp, vg, pav);
    hipLaunchKernelGGL(k_final,    dim3(1),        dim3(256),  0, stream, pav, Wo, bo, W1, b1, W2, b2, (float*)d_out);
}

// Round 7
// 301.230 us; speedup vs baseline: 1.6807x; 1.6807x over previous
//
#include <hip/hip_runtime.h>
#include <cstdint>
#include <cstddef>

#define NPTS 16384
#define KSEL 4096
#define HIDDEN 128
#define NHEADS 8
#define DHEAD 16
#define OUTD 256
#define NSLICE 4   // k/q slices for attn partials
#define FCAP 131072
#define LCAP 2048
#define TAU 0.2f

typedef __attribute__((ext_vector_type(8))) short bf16x8;
typedef __attribute__((ext_vector_type(4))) float f32x4;

#if defined(__has_builtin)
#if __has_builtin(__builtin_amdgcn_exp2f)
#define E2(x) __builtin_amdgcn_exp2f(x)
#endif
#endif
#ifndef E2
#define E2(x) exp2f(x)
#endif

// ---- workspace layout (bytes) ----
constexpr size_t OFF_PA    = 1024;                         // NPTS*16 bf16 (A-side packed)
constexpr size_t OFF_PB    = OFF_PA  + (size_t)NPTS*32;    // NPTS*16 bf16 (B-side packed)
constexpr size_t OFF_SQ    = OFF_PB  + (size_t)NPTS*32;
constexpr size_t OFF_DL    = OFF_SQ  + (size_t)NPTS*4;
constexpr size_t OFF_CNT   = OFF_DL  + (size_t)NPTS*4;     // int (memset 0)
constexpr size_t OFF_NFLAG = OFF_CNT + (size_t)NPTS*4;     // uint (memset 0, padded 1KB)
constexpr size_t OFF_FLG   = OFF_NFLAG + 1024;             // FCAP uints
constexpr size_t OFF_SEL   = OFF_FLG + (size_t)FCAP*4;     // KSEL int
constexpr size_t SZ_PK     = (size_t)NHEADS*KSEL*32*2;     // 2 MB packed [hi16|lo16] bf16
constexpr size_t OFF_QPK   = OFF_SEL + (size_t)KSEL*4;
constexpr size_t OFF_KPK   = OFF_QPK + SZ_PK;
constexpr size_t OFF_V     = OFF_KPK + SZ_PK;                      // KSEL*128 f32
constexpr size_t OFF_LP    = OFF_V  + (size_t)KSEL*HIDDEN*4;       // 8*4096*4 f32 partial l
constexpr size_t OFF_RL    = OFF_LP + (size_t)NHEADS*KSEL*NSLICE*4; // 8*4096 f32 1/l
constexpr size_t OFF_WP    = OFF_RL + (size_t)NHEADS*KSEL*4;        // 8*4096*4 f32 partial w
constexpr size_t OFF_PAV   = OFF_WP + (size_t)NHEADS*KSEL*NSLICE*4; // 128 f32

__device__ __forceinline__ unsigned short f2bf(float f) {
    union { float f; unsigned u; } v; v.f = f;
    unsigned r = v.u + 0x7fffu + ((v.u >> 16) & 1u);
    return (unsigned short)(r >> 16);
}
__device__ __forceinline__ float bf2f(unsigned short h) {
    union { unsigned u; float f; } v; v.u = ((unsigned)h) << 16;
    return v.f;
}

// ---- 1. prep: ligand center, sq, d_lig, packed hi/lo coords (+sq split) for MFMA d2 ----
__global__ void __launch_bounds__(256) k_prep(const float* __restrict__ pos, const float* __restrict__ lig, int M,
                       unsigned short* __restrict__ pa, unsigned short* __restrict__ pb,
                       float* __restrict__ sq, float* __restrict__ dl) {
    __shared__ float ls[128];
    __shared__ float ctr[3];
    int tid = threadIdx.x;
    for (int i = tid; i < 3 * M; i += 256) ls[i] = lig[i];
    __syncthreads();
    if (tid < 3) {
        float s = 0.f;
        for (int i = 0; i < M; i++) s += ls[i * 3 + tid];
        ctr[tid] = s / (float)M;
    }
    __syncthreads();
    int i = blockIdx.x * 256 + tid;
    float x = pos[i*3+0], y = pos[i*3+1], z = pos[i*3+2];
    float s = (x*x + y*y) + z*z;
    sq[i] = s;
    float dx = x - ctr[0], dy = y - ctr[1], dz = z - ctr[2];
    dl[i] = sqrtf((dx*dx + dy*dy) + dz*dz);
    // hi/lo split per coord
    unsigned short xh = f2bf(x); float xr = bf2f(xh); float xl = x - xr;
    unsigned short yh = f2bf(y); float yr = bf2f(yh); float yl = y - yr;
    unsigned short zh = f2bf(z); float zr = bf2f(zh); float zl = z - zr;
    unsigned short xlb = f2bf(xl), ylb = f2bf(yl), zlb = f2bf(zl);
    unsigned short xhA = f2bf(-2.f*xr), xlA = f2bf(-2.f*xl);
    unsigned short yhA = f2bf(-2.f*yr), ylA = f2bf(-2.f*yl);
    unsigned short zhA = f2bf(-2.f*zr), zlA = f2bf(-2.f*zl);
    unsigned short sih = f2bf(s);
    unsigned short sil = f2bf(s - bf2f(sih));
    unsigned short one = f2bf(1.0f);
    union { unsigned short s[16]; float4 f[2]; } A, B;
    // k-slot products: per coord (hh, h*lo_j, lo_i*h), 9-11 lo*lo, 12-13 si*1, 14-15 1*sj
    A.s[0]=xhA; A.s[1]=xhA; A.s[2]=xlA;
    A.s[3]=yhA; A.s[4]=yhA; A.s[5]=ylA;
    A.s[6]=zhA; A.s[7]=zhA; A.s[8]=zlA;
    A.s[9]=xlA; A.s[10]=ylA; A.s[11]=zlA;
    A.s[12]=sih; A.s[13]=sil; A.s[14]=one; A.s[15]=one;
    B.s[0]=xh;  B.s[1]=xlb;  B.s[2]=xh;
    B.s[3]=yh;  B.s[4]=ylb;  B.s[5]=yh;
    B.s[6]=zh;  B.s[7]=zlb;  B.s[8]=zh;
    B.s[9]=xlb; B.s[10]=ylb; B.s[11]=zlb;
    B.s[12]=one; B.s[13]=one; B.s[14]=sih; B.s[15]=sil;
    float4* pad = (float4*)(pa + (size_t)i * 16);
    pad[0] = A.f[0]; pad[1] = A.f[1];
    float4* pbd = (float4*)(pb + (size_t)i * 16);
    pbd[0] = B.f[0]; pbd[1] = B.f[1];
}

// ---- 2. neighbor counts via MFMA: c = si+sj-2*dot = d2 (all folded into K-slots) ----
// grid (igrp=256, jsplit=4), block 256 = 4 waves x 16 i-rows; boundary pairs -> LDS-staged flags
__global__ void __launch_bounds__(256) k_neighbor(
        const unsigned short* __restrict__ pa, const unsigned short* __restrict__ pb,
        int* __restrict__ cnt, unsigned int* __restrict__ flg, unsigned int* __restrict__ nflag) {
    __shared__ unsigned short bs[256 * 24];   // 48B row stride: 16B-aligned, 2-way aliasing only
    __shared__ unsigned int fbuf[LCAP];
    __shared__ unsigned int fcnt, fbase;
    int tid = threadIdx.x;
    if (tid == 0) fcnt = 0;
    int lane = tid & 63, w = tid >> 6;
    int n = lane & 15, g = lane >> 4;
    int i0 = blockIdx.x * 64 + w * 16;
    bf16x8 afrag = {0,0,0,0,0,0,0,0};
    if (g < 2) afrag = *(const bf16x8*)(pa + (size_t)(i0 + n) * 16 + g * 8);
    int irow = i0 + g * 4;
    int boff = (g < 2) ? g * 8 : 0;   // g>=2: read valid data, annihilated by A=0
    int jb0 = blockIdx.y * 4096;
    int c0 = 0, c1 = 0, c2 = 0, c3 = 0;
    for (int ch = 0; ch < 16; ch++) {
        __syncthreads();
        {
            const float4* src = (const float4*)(pb + (size_t)(jb0 + ch*256 + tid) * 16);
            float4 v0 = src[0], v1 = src[1];
            float4* dst = (float4*)&bs[tid * 24];
            dst[0] = v0; dst[1] = v1;
        }
        __syncthreads();
        int jb = jb0 + ch * 256;
        #pragma unroll 4
        for (int t = 0; t < 16; t++) {
            int jj = t * 16 + n;
            bf16x8 bfrag = *(const bf16x8*)&bs[jj * 24 + boff];
            f32x4 c = {0.f, 0.f, 0.f, 0.f};
            c = __builtin_amdgcn_mfma_f32_16x16x32_bf16(afrag, bfrag, c, 0, 0, 0);
            float d0 = c[0] - 9.0f, d1 = c[1] - 9.0f, d2_ = c[2] - 9.0f, d3 = c[3] - 9.0f;
            bool a0 = d0 < -TAU, a1 = d1 < -TAU, a2 = d2_ < -TAU, a3 = d3 < -TAU;
            bool f0 = (d0 < TAU) && !a0, f1 = (d1 < TAU) && !a1;
            bool f2 = (d2_ < TAU) && !a2, f3 = (d3 < TAU) && !a3;
            c0 += a0; c1 += a1; c2 += a2; c3 += a3;
            if (f0 | f1 | f2 | f3) {   // rare
                int j = jb + jj;
                if (f0) { unsigned xx = atomicAdd(&fcnt, 1u); if (xx < LCAP) fbuf[xx] = ((unsigned)(irow+0) << 14) | (unsigned)j; }
                if (f1) { unsigned xx = atomicAdd(&fcnt, 1u); if (xx < LCAP) fbuf[xx] = ((unsigned)(irow+1) << 14) | (unsigned)j; }
                if (f2) { unsigned xx = atomicAdd(&fcnt, 1u); if (xx < LCAP) fbuf[xx] = ((unsigned)(irow+2) << 14) | (unsigned)j; }
                if (f3) { unsigned xx = atomicAdd(&fcnt, 1u); if (xx < LCAP) fbuf[xx] = ((unsigned)(irow+3) << 14) | (unsigned)j; }
            }
        }
    }
    #pragma unroll
    for (int m = 1; m < 16; m <<= 1) {
        c0 += __shfl_xor(c0, m); c1 += __shfl_xor(c1, m);
        c2 += __shfl_xor(c2, m); c3 += __shfl_xor(c3, m);
    }
    if (n == 0) {
        atomicAdd(&cnt[irow+0], c0);
        atomicAdd(&cnt[irow+1], c1);
        atomicAdd(&cnt[irow+2], c2);
        atomicAdd(&cnt[irow+3], c3);
    }
    __syncthreads();
    if (tid == 0) {
        unsigned cf = fcnt; if (cf > LCAP) cf = LCAP;
        fcnt = cf;
        fbase = atomicAdd(nflag, cf);
    }
    __syncthreads();
    unsigned cf = fcnt, fb = fbase;
    for (unsigned xx = tid; xx < cf; xx += 256) {
        unsigned di = fb + xx;
        if (di < FCAP) flg[di] = fbuf[xx];
    }
}

// ---- 2b. resolve boundary-window pairs with the exact fp32 formula (matches R1-R3) ----
__global__ void __launch_bounds__(256) k_fixup(const float* __restrict__ pos, const float* __restrict__ sq,
        const unsigned int* __restrict__ flg, const unsigned int* __restrict__ nflag,
        int* __restrict__ cnt) {
    int nf = (int)*nflag; if (nf > FCAP) nf = FCAP;
    for (int idx = blockIdx.x * 256 + threadIdx.x; idx < nf; idx += gridDim.x * 256) {
        unsigned pr = flg[idx];
        int i = (int)(pr >> 14), j = (int)(pr & 16383u);
        float xi = pos[i*3+0], yi = pos[i*3+1], zi = pos[i*3+2];
        float xj = pos[j*3+0], yj = pos[j*3+1], zj = pos[j*3+2];
        float dot = fmaf(xi, xj, fmaf(yi, yj, zi * zj));
        float d2 = (sq[i] + sq[j]) - 2.0f * dot;
        if (d2 < 9.0f) atomicAdd(&cnt[i], 1);
    }
}

// ---- 3. scores (fused) + exact top-KSEL radix select (parallel suffix scan) ----
__global__ void __launch_bounds__(1024) k_select(const float* __restrict__ dl, const int* __restrict__ cnt,
                                                 int* __restrict__ sel) {
    __shared__ unsigned int sk[NPTS];
    __shared__ int hist[256];
    __shared__ int scan2[256];
    __shared__ unsigned int s_prefix;
    __shared__ int s_rem, s_eqtot, s_nout, s_digit, s_cgt;
    int tid = threadIdx.x;
    for (int i = tid; i < NPTS; i += 1024) {
        float score = 1.0f / (1.0f + dl[i] / 5.0f) + 0.5f * (1.0f / (float)cnt[i]);
        unsigned int u = __float_as_uint(score);
        sk[i] = u ^ ((u & 0x80000000u) ? 0xFFFFFFFFu : 0x80000000u);
    }
    if (tid == 0) { s_prefix = 0; s_rem = KSEL; s_nout = 0; s_eqtot = 0; }
    __syncthreads();
    for (int p = 0; p < 4; p++) {
        int sh = 24 - 8 * p;
        if (tid < 256) hist[tid] = 0;
        __syncthreads();
        unsigned int pref = s_prefix;
        int shp = (p == 0) ? 0 : (32 - 8 * p);
        for (int i = tid; i < NPTS; i += 1024) {
            unsigned int key = sk[i];
            bool m = (p == 0) || ((key >> shp) == pref);
            if (m) atomicAdd(&hist[(key >> sh) & 255], 1);
        }
        __syncthreads();
        if (tid < 256) scan2[tid] = hist[tid];
        __syncthreads();
        for (int off = 1; off < 256; off <<= 1) {
            int v = 0;
            if (tid < 256) { v = scan2[tid]; if (tid + off < 256) v += scan2[tid + off]; }
            __syncthreads();
            if (tid < 256) scan2[tid] = v;
            __syncthreads();
        }
        int rem = s_rem;
        if (tid < 256) {
            int hi = scan2[tid];          // sum_{d' >= tid}
            int lo = hi - hist[tid];      // sum_{d' > tid}
            if (hi >= rem && lo < rem) { s_digit = tid; s_cgt = lo; }
        }
        __syncthreads();
        if (tid == 0) {
            s_prefix = (s_prefix << 8) | (unsigned int)s_digit;
            s_rem = rem - s_cgt;
            if (p == 3) s_eqtot = hist[s_digit];
        }
        __syncthreads();
    }
    unsigned int T = s_prefix;
    int need_eq = s_rem;
    for (int i = tid; i < NPTS; i += 1024)
        if (sk[i] > T) sel[atomicAdd(&s_nout, 1)] = i;
    __syncthreads();
    if (s_eqtot == need_eq) {
        for (int i = tid; i < NPTS; i += 1024)
            if (sk[i] == T) sel[atomicAdd(&s_nout, 1)] = i;
    } else {
        for (int i = tid; i < NPTS; i += 1024) {
            if (sk[i] == T) {
                int rank = 0;
                for (int j = 0; j < i; j++) rank += (sk[j] == T);
                if (rank < need_eq) sel[atomicAdd(&s_nout, 1)] = i;
            }
        }
    }
}

// ---- 4. gather + node embed + QKV projections; Q/K -> packed bf16 [hi16|lo16] rows ----
__device__ __forceinline__ void proj8(const float hs[8][HIDDEN], const float* __restrict__ W,
                                      float b, int d, float* acc) {
    #pragma unroll
    for (int r = 0; r < 8; r++) acc[r] = b;
    for (int c = 0; c < HIDDEN; c += 4) {
        float w0 = W[(c+0)*HIDDEN+d], w1 = W[(c+1)*HIDDEN+d], w2 = W[(c+2)*HIDDEN+d], w3 = W[(c+3)*HIDDEN+d];
        #pragma unroll
        for (int r = 0; r < 8; r++) {
            float4 h4 = *(const float4*)&hs[r][c];
            float a = acc[r];
            a = fmaf(h4.x, w0, a); a = fmaf(h4.y, w1, a); a = fmaf(h4.z, w2, a); a = fmaf(h4.w, w3, a);
            acc[r] = a;
        }
    }
}

__global__ void __launch_bounds__(128) k_qkv(const float* __restrict__ x, const int* __restrict__ sel,
        const float* __restrict__ Wn, const float* __restrict__ bn,
        const float* __restrict__ Wq, const float* __restrict__ bq,
        const float* __restrict__ Wk, const float* __restrict__ bk,
        const float* __restrict__ Wv, const float* __restrict__ bv,
        unsigned short* __restrict__ qpk, unsigned short* __restrict__ kpk,
        float* __restrict__ vg) {
    __shared__ float xs[8][8];
    __shared__ __align__(16) float hs[8][HIDDEN];
    int d = threadIdx.x;
    int r0 = blockIdx.x * 8;
    if (d < 64) { int rr = d >> 3, cc = d & 7; xs[rr][cc] = x[(size_t)sel[r0 + rr] * 8 + cc]; }
    __syncthreads();
    {
        float wn[8];
        #pragma unroll
        for (int c = 0; c < 8; c++) wn[c] = Wn[c * HIDDEN + d];
        float b = bn[d];
        #pragma unroll
        for (int r = 0; r < 8; r++) {
            float a = b;
            #pragma unroll
            for (int c = 0; c < 8; c++) a = fmaf(xs[r][c], wn[c], a);
            hs[r][d] = a;
        }
    }
    __syncthreads();
    int hh = d >> 4, dd = d & 15;
    float acc[8];
    // Q (pre-scaled by log2(e)/4, split hi/lo)
    proj8(hs, Wq, bq[d], d, acc);
    #pragma unroll
    for (int r = 0; r < 8; r++) {
        float val = acc[r] * 0.36067376022224085f;
        unsigned short hi = f2bf(val);
        unsigned short lo = f2bf(val - bf2f(hi));
        size_t idx = ((size_t)(hh * KSEL) + r0 + r) * 32 + dd;
        qpk[idx] = hi; qpk[idx + 16] = lo;
    }
    // K
    proj8(hs, Wk, bk[d], d, acc);
    #pragma unroll
    for (int r = 0; r < 8; r++) {
        float val = acc[r];
        unsigned short hi = f2bf(val);
        unsigned short lo = f2bf(val - bf2f(hi));
        size_t idx = ((size_t)(hh * KSEL) + r0 + r) * 32 + dd;
        kpk[idx] = hi; kpk[idx + 16] = lo;
    }
    // V (fp32, row-major [q][128])
    proj8(hs, Wv, bv[d], d, acc);
    #pragma unroll
    for (int r = 0; r < 8; r++) vg[(size_t)(r0+r)*HIDDEN + d] = acc[r];
}

// ---- 5. phase 1: row sums l_q via MFMA; chunked LDS (256 rows, 80B stride) ----
__global__ void __launch_bounds__(256) k_attn_l(
        const unsigned short* __restrict__ qpk, const unsigned short* __restrict__ kpk,
        float* __restrict__ lp) {
    __shared__ unsigned short smem[256 * 40];
    int tid = threadIdx.x;
    int ks = blockIdx.x, yg = blockIdx.y, h = blockIdx.z;
    size_t hb = (size_t)h * KSEL;
    int lane = tid & 63, w = tid >> 6;
    int n = lane & 15, g = lane >> 4;
    int q0w = yg * 64 + w * 16;
    bf16x8 afrag = *(const bf16x8*)(qpk + (hb + q0w + n) * 32 + g * 8); // A=[Qh|Ql]
    float l0 = 0.f, l1 = 0.f, l2 = 0.f, l3 = 0.f;
    int b1off = (g & 1) * 8;
    int b2off = 16 + g * 8;
    for (int kc = 0; kc < 4; kc++) {
        __syncthreads();
        {
            int krow = ks * 1024 + kc * 256 + tid;
            const float4* src = (const float4*)(kpk + (hb + krow) * 32);
            float4 a0 = src[0], a1 = src[1], a2 = src[2], a3 = src[3];
            float4* dst = (float4*)&smem[tid * 40];
            dst[0] = a0; dst[1] = a1; dst[2] = a2; dst[3] = a3;
        }
        __syncthreads();
        #pragma unroll 4
        for (int t = 0; t < 16; t++) {
            const unsigned short* rowp = &smem[(t * 16 + n) * 40];
            bf16x8 b1 = *(const bf16x8*)(rowp + b1off);            // [Kh|Kh]
            bf16x8 b2 = {0,0,0,0,0,0,0,0};                          // [Kl|0]
            if (g < 2) b2 = *(const bf16x8*)(rowp + b2off);
            f32x4 c = {0.f, 0.f, 0.f, 0.f};
            c = __builtin_amdgcn_mfma_f32_16x16x32_bf16(afrag, b1, c, 0, 0, 0);
            c = __builtin_amdgcn_mfma_f32_16x16x32_bf16(afrag, b2, c, 0, 0, 0);
            l0 += E2(c[0]); l1 += E2(c[1]); l2 += E2(c[2]); l3 += E2(c[3]);
        }
    }
    #pragma unroll
    for (int m = 1; m < 16; m <<= 1) {
        l0 += __shfl_xor(l0, m); l1 += __shfl_xor(l1, m);
        l2 += __shfl_xor(l2, m); l3 += __shfl_xor(l3, m);
    }
    if (n == 0) {
        size_t base = (hb + q0w + g * 4) * NSLICE + ks;
        lp[base]            = l0; lp[base + NSLICE]     = l1;
        lp[base + 2*NSLICE] = l2; lp[base + 3*NSLICE]   = l3;
    }
}

// ---- 6. combine l partials -> 1/l ----
__global__ void k_rl(const float* __restrict__ lp, float* __restrict__ rl) {
    int i = blockIdx.x * 256 + threadIdx.x;
    float4 p = ((const float4*)lp)[i];
    rl[i] = 1.0f / ((p.x + p.y) + (p.z + p.w));
}

// ---- 7. phase 2: column weights w_j = sum_q exp(s)/l_q (A = K-row [Kh|Kl]) ----
__global__ void __launch_bounds__(256) k_attn_w(
        const unsigned short* __restrict__ qpk, const unsigned short* __restrict__ kpk,
        const float* __restrict__ rl, float* __restrict__ wp) {
    __shared__ unsigned short smem[256 * 40];
    __shared__ float rls[256];
    int tid = threadIdx.x;
    int qs = blockIdx.x, yg = blockIdx.y, h = blockIdx.z;
    size_t hb = (size_t)h * KSEL;
    int lane = tid & 63, w = tid >> 6;
    int n = lane & 15, g = lane >> 4;
    int j0w = yg * 64 + w * 16;
    bf16x8 afrag = *(const bf16x8*)(kpk + (hb + j0w + n) * 32 + g * 8); // A=[Kh|Kl]
    float w0 = 0.f, w1 = 0.f, w2 = 0.f, w3 = 0.f;
    int b1off = (g & 1) * 8;
    int b2off = 16 + g * 8;
    for (int qc = 0; qc < 4; qc++) {
        __syncthreads();
        {
            int qrow = qs * 1024 + qc * 256 + tid;
            const float4* src = (const float4*)(qpk + (hb + qrow) * 32);
            float4 a0 = src[0], a1 = src[1], a2 = src[2], a3 = src[3];
            float4* dst = (float4*)&smem[tid * 40];
            dst[0] = a0; dst[1] = a1; dst[2] = a2; dst[3] = a3;
            rls[tid] = rl[hb + qrow];
        }
        __syncthreads();
        #pragma unroll 4
        for (int t = 0; t < 16; t++) {
            const unsigned short* rowp = &smem[(t * 16 + n) * 40];
            bf16x8 b1 = *(const bf16x8*)(rowp + b1off);            // [Qh|Qh]
            bf16x8 b2 = {0,0,0,0,0,0,0,0};                          // [Ql|0]
            if (g < 2) b2 = *(const bf16x8*)(rowp + b2off);
            f32x4 c = {0.f, 0.f, 0.f, 0.f};
            c = __builtin_amdgcn_mfma_f32_16x16x32_bf16(afrag, b1, c, 0, 0, 0);
            c = __builtin_amdgcn_mfma_f32_16x16x32_bf16(afrag, b2, c, 0, 0, 0);
            float rv = rls[t * 16 + n];
            w0 = fmaf(E2(c[0]), rv, w0); w1 = fmaf(E2(c[1]), rv, w1);
            w2 = fmaf(E2(c[2]), rv, w2); w3 = fmaf(E2(c[3]), rv, w3);
        }
    }
    #pragma unroll
    for (int m = 1; m < 16; m <<= 1) {
        w0 += __shfl_xor(w0, m); w1 += __shfl_xor(w1, m);
        w2 += __shfl_xor(w2, m); w3 += __shfl_xor(w3, m);
    }
    if (n == 0) {
        size_t base = (hb + j0w + g * 4) * NSLICE + qs;
        wp[base]            = w0; wp[base + NSLICE]     = w1;
        wp[base + 2*NSLICE] = w2; wp[base + 3*NSLICE]   = w3;
    }
}

// ---- 8. pooled_av[d] += (1/K) sum_j w[h(d)][j] * v[j][d] ----
__global__ void __launch_bounds__(256) k_colsum(const float* __restrict__ wp, const float* __restrict__ vg,
                                                float* __restrict__ pav) {
    __shared__ float wl[NHEADS][128];
    __shared__ float red[128];
    int tid = threadIdx.x;
    int jb = blockIdx.x * 128;
    for (int i = tid; i < NHEADS * 128; i += 256) {
        int h = i >> 7, jl = i & 127;
        float4 p = ((const float4*)wp)[(size_t)h * KSEL + jb + jl];
        wl[h][jl] = (p.x + p.y) + (p.z + p.w);
    }
    __syncthreads();
    int d = tid & 127, g = tid >> 7;
    int h = d >> 4;
    float acc = 0.f;
    for (int jl = g * 64; jl < g * 64 + 64; jl++)
        acc = fmaf(wl[h][jl], vg[(size_t)(jb + jl) * HIDDEN + d], acc);
    if (g == 1) red[d] = acc;
    __syncthreads();
    if (g == 0) atomicAdd(&pav[d], (acc + red[d]) * (1.0f / (float)KSEL));
}

// ---- 9. out-proj + pool MLP ----
__global__ void __launch_bounds__(256) k_final(const float* __restrict__ pav,
        const float* __restrict__ Wo, const float* __restrict__ bo,
        const float* __restrict__ W1, const float* __restrict__ b1,
        const float* __restrict__ W2, const float* __restrict__ b2,
        float* __restrict__ out) {
    __shared__ float sp[HIDDEN];
    __shared__ float st[OUTD];
    int t = threadIdx.x;
    if (t < HIDDEN) {
        float a = bo[t];
        for (int c = 0; c < HIDDEN; c++) a = fmaf(pav[c], Wo[c * HIDDEN + t], a);
        sp[t] = a;
    }
    __syncthreads();
    {
        float a = b1[t];
        for (int c = 0; c < HIDDEN; c++) a = fmaf(sp[c], W1[c * OUTD + t], a);
        st[t] = fmaxf(a, 0.f);
    }
    __syncthreads();
    {
        float o = b2[t];
        for (int c = 0; c < OUTD; c++) o = fmaf(st[c], W2[c * OUTD + t], o);
        out[t] = o;
    }
}

extern "C" void kernel_launch(void* const* d_in, const int* in_sizes, int n_in,
                              void* d_out, int out_size, void* d_ws, size_t ws_size,
                              hipStream_t stream) {
    (void)n_in; (void)out_size; (void)ws_size;
    const float* x   = (const float*)d_in[0];
    const float* pos = (const float*)d_in[1];
    const float* lig = (const float*)d_in[2];
    const float* Wn  = (const float*)d_in[3];
    const float* bn  = (const float*)d_in[4];
    const float* Wq  = (const float*)d_in[5];
    const float* bq  = (const float*)d_in[6];
    const float* Wk  = (const float*)d_in[7];
    const float* bk  = (const float*)d_in[8];
    const float* Wv  = (const float*)d_in[9];
    const float* bv  = (const float*)d_in[10];
    const float* Wo  = (const float*)d_in[11];
    const float* bo  = (const float*)d_in[12];
    const float* W1  = (const float*)d_in[13];
    const float* b1  = (const float*)d_in[14];
    const float* W2  = (const float*)d_in[15];
    const float* b2  = (const float*)d_in[16];
    int M = in_sizes[2] / 3;

    char* ws = (char*)d_ws;
    unsigned short* pa  = (unsigned short*)(ws + OFF_PA);
    unsigned short* pb  = (unsigned short*)(ws + OFF_PB);
    float*          sq  = (float*)(ws + OFF_SQ);
    float*          dl  = (float*)(ws + OFF_DL);
    int*            cnt = (int*)  (ws + OFF_CNT);
    unsigned int*   nfl = (unsigned int*)(ws + OFF_NFLAG);
    unsigned int*   flg = (unsigned int*)(ws + OFF_FLG);
    int*            sel = (int*)  (ws + OFF_SEL);
    unsigned short* qpk = (unsigned short*)(ws + OFF_QPK);
    unsigned short* kpk = (unsigned short*)(ws + OFF_KPK);
    float*          vg  = (float*)(ws + OFF_V);
    float*          lp  = (float*)(ws + OFF_LP);
    float*          rl  = (float*)(ws + OFF_RL);
    float*          wp  = (float*)(ws + OFF_WP);
    float*          pav = (float*)(ws + OFF_PAV);

    hipMemsetAsync(ws + OFF_CNT, 0, (size_t)NPTS * 4 + 1024, stream);  // cnt + nflag
    hipMemsetAsync(ws + OFF_PAV, 0, (size_t)HIDDEN * 4, stream);

    hipLaunchKernelGGL(k_prep,     dim3(64),       dim3(256),  0, stream, pos, lig, M, pa, pb, sq, dl);
    hipLaunchKernelGGL(k_neighbor, dim3(256, 4),   dim3(256),  0, stream, pa, pb, cnt, flg, nfl);
    hipLaunchKernelGGL(k_fixup,    dim3(32),       dim3(256),  0, stream, pos, sq, flg, nfl, cnt);
    hipLaunchKernelGGL(k_select,   dim3(1),        dim3(1024), 0, stream, dl, cnt, sel);
    hipLaunchKernelGGL(k_qkv,      dim3(KSEL/8),   dim3(128),  0, stream, x, sel, Wn, bn, Wq, bq, Wk, bk, Wv, bv, qpk, kpk, vg);
    hipLaunchKernelGGL(k_attn_l,   dim3(4, 64, 8), dim3(256),  0, stream, qpk, kpk, lp);
    hipLaunchKernelGGL(k_rl,       dim3(NHEADS*KSEL/256), dim3(256), 0, stream, lp, rl);
    hipLaunchKernelGGL(k_attn_w,   dim3(4, 64, 8), dim3(256),  0, stream, qpk, kpk, rl, wp);
    hipLaunchKernelGGL(k_colsum,   dim3(32),       dim3(256),  0, stream, wp, vg, pav);
    hipLaunchKernelGGL(k_final,    dim3(1),        dim3(256),  0, stream, pav, Wo, bo, W1, b1, W2, b2, (float*)d_out);
}

// Round 8
// 294.376 us; speedup vs baseline: 1.7198x; 1.0233x over previous
//
#include <hip/hip_runtime.h>
#include <cstdint>
#include <cstddef>

#define NPTS 16384
#define KSEL 4096
#define HIDDEN 128
#define NHEADS 8
#define DHEAD 16
#define OUTD 256
#define NSLICE 4   // k/q slices for attn partials
#define FCAP 131072
#define LCAP 2048
#define TAU 0.2f

typedef __attribute__((ext_vector_type(8))) short bf16x8;
typedef __attribute__((ext_vector_type(4))) float f32x4;

#if defined(__has_builtin)
#if __has_builtin(__builtin_amdgcn_exp2f)
#define E2(x) __builtin_amdgcn_exp2f(x)
#endif
#endif
#ifndef E2
#define E2(x) exp2f(x)
#endif

// ---- workspace layout (bytes) ----
constexpr size_t OFF_PA    = 1024;                         // NPTS*16 bf16 (A-side packed)
constexpr size_t OFF_PB    = OFF_PA  + (size_t)NPTS*32;    // NPTS*16 bf16 (B-side packed)
constexpr size_t OFF_SQ    = OFF_PB  + (size_t)NPTS*32;
constexpr size_t OFF_DL    = OFF_SQ  + (size_t)NPTS*4;
constexpr size_t OFF_CNT   = OFF_DL  + (size_t)NPTS*4;     // int (memset 0)
constexpr size_t OFF_NFLAG = OFF_CNT + (size_t)NPTS*4;     // uint (memset 0, padded 1KB)
constexpr size_t OFF_FLG   = OFF_NFLAG + 1024;             // FCAP uints
constexpr size_t OFF_SEL   = OFF_FLG + (size_t)FCAP*4;     // KSEL int
constexpr size_t SZ_PK     = (size_t)NHEADS*KSEL*32*2;     // 2 MB packed [hi16|lo16] bf16
constexpr size_t OFF_QPK   = OFF_SEL + (size_t)KSEL*4;
constexpr size_t OFF_KPK   = OFF_QPK + SZ_PK;
constexpr size_t OFF_V     = OFF_KPK + SZ_PK;                      // KSEL*128 f32
constexpr size_t OFF_LP    = OFF_V  + (size_t)KSEL*HIDDEN*4;       // 8*4096*4 f32 partial l
constexpr size_t OFF_RL    = OFF_LP + (size_t)NHEADS*KSEL*NSLICE*4; // 8*4096 f32 1/l
constexpr size_t OFF_WP    = OFF_RL + (size_t)NHEADS*KSEL*4;        // 8*4096*4 f32 partial w
constexpr size_t OFF_PAV   = OFF_WP + (size_t)NHEADS*KSEL*NSLICE*4; // 128 f32

__device__ __forceinline__ unsigned short f2bf(float f) {
    union { float f; unsigned u; } v; v.f = f;
    unsigned r = v.u + 0x7fffu + ((v.u >> 16) & 1u);
    return (unsigned short)(r >> 16);
}
__device__ __forceinline__ float bf2f(unsigned short h) {
    union { unsigned u; float f; } v; v.u = ((unsigned)h) << 16;
    return v.f;
}

// ---- 1. prep: ligand center, sq, d_lig, packed hi/lo coords (+sq split) for MFMA d2 ----
__global__ void __launch_bounds__(256) k_prep(const float* __restrict__ pos, const float* __restrict__ lig, int M,
                       unsigned short* __restrict__ pa, unsigned short* __restrict__ pb,
                       float* __restrict__ sq, float* __restrict__ dl) {
    __shared__ float ls[128];
    __shared__ float ctr[3];
    int tid = threadIdx.x;
    for (int i = tid; i < 3 * M; i += 256) ls[i] = lig[i];
    __syncthreads();
    if (tid < 3) {
        float s = 0.f;
        for (int i = 0; i < M; i++) s += ls[i * 3 + tid];
        ctr[tid] = s / (float)M;
    }
    __syncthreads();
    int i = blockIdx.x * 256 + tid;
    float x = pos[i*3+0], y = pos[i*3+1], z = pos[i*3+2];
    float s = (x*x + y*y) + z*z;
    sq[i] = s;
    float dx = x - ctr[0], dy = y - ctr[1], dz = z - ctr[2];
    dl[i] = sqrtf((dx*dx + dy*dy) + dz*dz);
    unsigned short xh = f2bf(x); float xr = bf2f(xh); float xl = x - xr;
    unsigned short yh = f2bf(y); float yr = bf2f(yh); float yl = y - yr;
    unsigned short zh = f2bf(z); float zr = bf2f(zh); float zl = z - zr;
    unsigned short xlb = f2bf(xl), ylb = f2bf(yl), zlb = f2bf(zl);
    unsigned short xhA = f2bf(-2.f*xr), xlA = f2bf(-2.f*xl);
    unsigned short yhA = f2bf(-2.f*yr), ylA = f2bf(-2.f*yl);
    unsigned short zhA = f2bf(-2.f*zr), zlA = f2bf(-2.f*zl);
    unsigned short sih = f2bf(s);
    unsigned short sil = f2bf(s - bf2f(sih));
    unsigned short one = f2bf(1.0f);
    union { unsigned short s[16]; float4 f[2]; } A, B;
    // k-slots: per coord (hh, h*lo_j, lo_i*h), 9-11 lo*lo, 12-13 si*1, 14-15 1*sj
    A.s[0]=xhA; A.s[1]=xhA; A.s[2]=xlA;
    A.s[3]=yhA; A.s[4]=yhA; A.s[5]=ylA;
    A.s[6]=zhA; A.s[7]=zhA; A.s[8]=zlA;
    A.s[9]=xlA; A.s[10]=ylA; A.s[11]=zlA;
    A.s[12]=sih; A.s[13]=sil; A.s[14]=one; A.s[15]=one;
    B.s[0]=xh;  B.s[1]=xlb;  B.s[2]=xh;
    B.s[3]=yh;  B.s[4]=ylb;  B.s[5]=yh;
    B.s[6]=zh;  B.s[7]=zlb;  B.s[8]=zh;
    B.s[9]=xlb; B.s[10]=ylb; B.s[11]=zlb;
    B.s[12]=one; B.s[13]=one; B.s[14]=sih; B.s[15]=sil;
    float4* pad = (float4*)(pa + (size_t)i * 16);
    pad[0] = A.f[0]; pad[1] = A.f[1];
    float4* pbd = (float4*)(pb + (size_t)i * 16);
    pbd[0] = B.f[0]; pbd[1] = B.f[1];
}

// ---- 2. neighbor counts via MFMA, UPPER TRIANGLE ONLY (symmetry): row + column counts ----
// grid (strip=256 of 64 rows, chunk=8 of 2048 j), block 256 = 4 waves x 16 i-rows
__global__ void __launch_bounds__(256) k_neighbor(
        const unsigned short* __restrict__ pa, const unsigned short* __restrict__ pb,
        int* __restrict__ cnt, unsigned int* __restrict__ flg, unsigned int* __restrict__ nflag) {
    int s = blockIdx.x, ch = blockIdx.y;
    int jb0 = ch * 2048;
    if (jb0 + 2048 <= s * 64) return;            // chunk entirely below diagonal (uniform)
    __shared__ unsigned short bs[256 * 24];      // 48B stride: 16B-aligned
    __shared__ int colcnt[2048];
    __shared__ unsigned int fbuf[LCAP];
    __shared__ unsigned int fcnt, fbase;
    int tid = threadIdx.x;
    for (int i = tid; i < 2048; i += 256) colcnt[i] = 0;
    if (tid == 0) fcnt = 0;
    int lane = tid & 63, w = tid >> 6;
    int n = lane & 15, g = lane >> 4;
    int i0 = s * 64 + w * 16;                    // this wave's row-tile base
    bf16x8 afrag = {0,0,0,0,0,0,0,0};
    if (g < 2) afrag = *(const bf16x8*)(pa + (size_t)(i0 + n) * 16 + g * 8);
    int irow = i0 + g * 4;
    int boff = (g < 2) ? g * 8 : 0;              // g>=2: valid data, annihilated by A=0
    int c0 = 0, c1 = 0, c2 = 0, c3 = 0;
    for (int sub = 0; sub < 8; sub++) {
        int jb = jb0 + sub * 256;
        if (jb + 256 <= s * 64) continue;        // subchunk below strip (block-uniform)
        __syncthreads();
        {
            const float4* src = (const float4*)(pb + (size_t)(jb + tid) * 16);
            float4 v0 = src[0], v1 = src[1];
            float4* dst = (float4*)&bs[tid * 24];
            dst[0] = v0; dst[1] = v1;
        }
        __syncthreads();
        for (int t = 0; t < 16; t++) {
            int jt = jb + t * 16;                // j-tile base
            if (jt < i0) continue;               // below this wave's diagonal (wave-uniform)
            bool sym = (jt > i0);
            bf16x8 bfrag = *(const bf16x8*)&bs[(t * 16 + n) * 24 + boff];
            f32x4 c = {0.f, 0.f, 0.f, 0.f};
            c = __builtin_amdgcn_mfma_f32_16x16x32_bf16(afrag, bfrag, c, 0, 0, 0);
            bool a0 = c[0] < (9.0f - TAU), a1 = c[1] < (9.0f - TAU);
            bool a2 = c[2] < (9.0f - TAU), a3 = c[3] < (9.0f - TAU);
            bool f0 = (c[0] < 9.0f + TAU) && !a0, f1 = (c[1] < 9.0f + TAU) && !a1;
            bool f2 = (c[2] < 9.0f + TAU) && !a2, f3 = (c[3] < 9.0f + TAU) && !a3;
            c0 += a0; c1 += a1; c2 += a2; c3 += a3;
            if (sym) {                           // column counts for rows j (uniform branch)
                int sl = (int)a0 + (int)a1 + (int)a2 + (int)a3;
                sl += __shfl_xor(sl, 16);
                sl += __shfl_xor(sl, 32);
                if (g == 0 && sl != 0) atomicAdd(&colcnt[jt - jb0 + n], sl);
            }
            if (f0 | f1 | f2 | f3) {             // rare boundary pairs
                unsigned sb = sym ? (1u << 28) : 0u;
                int j = jt + n;
                if (f0) { unsigned xx = atomicAdd(&fcnt, 1u); if (xx < LCAP) fbuf[xx] = sb | ((unsigned)(irow+0) << 14) | (unsigned)j; }
                if (f1) { unsigned xx = atomicAdd(&fcnt, 1u); if (xx < LCAP) fbuf[xx] = sb | ((unsigned)(irow+1) << 14) | (unsigned)j; }
                if (f2) { unsigned xx = atomicAdd(&fcnt, 1u); if (xx < LCAP) fbuf[xx] = sb | ((unsigned)(irow+2) << 14) | (unsigned)j; }
                if (f3) { unsigned xx = atomicAdd(&fcnt, 1u); if (xx < LCAP) fbuf[xx] = sb | ((unsigned)(irow+3) << 14) | (unsigned)j; }
            }
        }
    }
    #pragma unroll
    for (int m = 1; m < 16; m <<= 1) {
        c0 += __shfl_xor(c0, m); c1 += __shfl_xor(c1, m);
        c2 += __shfl_xor(c2, m); c3 += __shfl_xor(c3, m);
    }
    if (n == 0) {
        if (c0) atomicAdd(&cnt[irow+0], c0);
        if (c1) atomicAdd(&cnt[irow+1], c1);
        if (c2) atomicAdd(&cnt[irow+2], c2);
        if (c3) atomicAdd(&cnt[irow+3], c3);
    }
    __syncthreads();
    for (int i = tid; i < 2048; i += 256) {
        int v = colcnt[i];
        if (v) atomicAdd(&cnt[jb0 + i], v);
    }
    if (tid == 0) {
        unsigned cf = fcnt; if (cf > LCAP) cf = LCAP;
        fcnt = cf;
        fbase = atomicAdd(nflag, cf);
    }
    __syncthreads();
    unsigned cf = fcnt, fb = fbase;
    for (unsigned xx = tid; xx < cf; xx += 256) {
        unsigned di = fb + xx;
        if (di < FCAP) flg[di] = fbuf[xx];
    }
}

// ---- 2b. resolve boundary-window pairs exactly (fp32); sym pairs update both rows ----
__global__ void __launch_bounds__(256) k_fixup(const float* __restrict__ pos, const float* __restrict__ sq,
        const unsigned int* __restrict__ flg, const unsigned int* __restrict__ nflag,
        int* __restrict__ cnt) {
    int nf = (int)*nflag; if (nf > FCAP) nf = FCAP;
    for (int idx = blockIdx.x * 256 + threadIdx.x; idx < nf; idx += gridDim.x * 256) {
        unsigned pr = flg[idx];
        int i = (int)((pr >> 14) & 16383u), j = (int)(pr & 16383u);
        float xi = pos[i*3+0], yi = pos[i*3+1], zi = pos[i*3+2];
        float xj = pos[j*3+0], yj = pos[j*3+1], zj = pos[j*3+2];
        float dot = fmaf(xi, xj, fmaf(yi, yj, zi * zj));
        float d2 = (sq[i] + sq[j]) - 2.0f * dot;
        if (d2 < 9.0f) {
            atomicAdd(&cnt[i], 1);
            if (pr & (1u << 28)) atomicAdd(&cnt[j], 1);
        }
    }
}

// ---- 3. scores (fused) + exact top-KSEL radix select (parallel suffix scan) ----
__global__ void __launch_bounds__(1024) k_select(const float* __restrict__ dl, const int* __restrict__ cnt,
                                                 int* __restrict__ sel) {
    __shared__ unsigned int sk[NPTS];
    __shared__ int hist[256];
    __shared__ int scan2[256];
    __shared__ unsigned int s_prefix;
    __shared__ int s_rem, s_eqtot, s_nout, s_digit, s_cgt;
    int tid = threadIdx.x;
    for (int i = tid; i < NPTS; i += 1024) {
        float score = 1.0f / (1.0f + dl[i] / 5.0f) + 0.5f * (1.0f / (float)cnt[i]);
        unsigned int u = __float_as_uint(score);
        sk[i] = u ^ ((u & 0x80000000u) ? 0xFFFFFFFFu : 0x80000000u);
    }
    if (tid == 0) { s_prefix = 0; s_rem = KSEL; s_nout = 0; s_eqtot = 0; }
    __syncthreads();
    for (int p = 0; p < 4; p++) {
        int sh = 24 - 8 * p;
        if (tid < 256) hist[tid] = 0;
        __syncthreads();
        unsigned int pref = s_prefix;
        int shp = (p == 0) ? 0 : (32 - 8 * p);
        for (int i = tid; i < NPTS; i += 1024) {
            unsigned int key = sk[i];
            bool m = (p == 0) || ((key >> shp) == pref);
            if (m) atomicAdd(&hist[(key >> sh) & 255], 1);
        }
        __syncthreads();
        if (tid < 256) scan2[tid] = hist[tid];
        __syncthreads();
        for (int off = 1; off < 256; off <<= 1) {
            int v = 0;
            if (tid < 256) { v = scan2[tid]; if (tid + off < 256) v += scan2[tid + off]; }
            __syncthreads();
            if (tid < 256) scan2[tid] = v;
            __syncthreads();
        }
        int rem = s_rem;
        if (tid < 256) {
            int hi = scan2[tid];
            int lo = hi - hist[tid];
            if (hi >= rem && lo < rem) { s_digit = tid; s_cgt = lo; }
        }
        __syncthreads();
        if (tid == 0) {
            s_prefix = (s_prefix << 8) | (unsigned int)s_digit;
            s_rem = rem - s_cgt;
            if (p == 3) s_eqtot = hist[s_digit];
        }
        __syncthreads();
    }
    unsigned int T = s_prefix;
    int need_eq = s_rem;
    for (int i = tid; i < NPTS; i += 1024)
        if (sk[i] > T) sel[atomicAdd(&s_nout, 1)] = i;
    __syncthreads();
    if (s_eqtot == need_eq) {
        for (int i = tid; i < NPTS; i += 1024)
            if (sk[i] == T) sel[atomicAdd(&s_nout, 1)] = i;
    } else {
        for (int i = tid; i < NPTS; i += 1024) {
            if (sk[i] == T) {
                int rank = 0;
                for (int j = 0; j < i; j++) rank += (sk[j] == T);
                if (rank < need_eq) sel[atomicAdd(&s_nout, 1)] = i;
            }
        }
    }
}

// ---- 4. gather + node embed + QKV projections (4 rows/block for 2 waves/SIMD) ----
__device__ __forceinline__ void proj4(const float hs[4][HIDDEN], const float* __restrict__ W,
                                      float b, int d, float* acc) {
    #pragma unroll
    for (int r = 0; r < 4; r++) acc[r] = b;
    for (int c = 0; c < HIDDEN; c += 4) {
        float w0 = W[(c+0)*HIDDEN+d], w1 = W[(c+1)*HIDDEN+d], w2 = W[(c+2)*HIDDEN+d], w3 = W[(c+3)*HIDDEN+d];
        #pragma unroll
        for (int r = 0; r < 4; r++) {
            float4 h4 = *(const float4*)&hs[r][c];
            float a = acc[r];
            a = fmaf(h4.x, w0, a); a = fmaf(h4.y, w1, a); a = fmaf(h4.z, w2, a); a = fmaf(h4.w, w3, a);
            acc[r] = a;
        }
    }
}

__global__ void __launch_bounds__(128) k_qkv(const float* __restrict__ x, const int* __restrict__ sel,
        const float* __restrict__ Wn, const float* __restrict__ bn,
        const float* __restrict__ Wq, const float* __restrict__ bq,
        const float* __restrict__ Wk, const float* __restrict__ bk,
        const float* __restrict__ Wv, const float* __restrict__ bv,
        unsigned short* __restrict__ qpk, unsigned short* __restrict__ kpk,
        float* __restrict__ vg) {
    __shared__ float xs[4][8];
    __shared__ __align__(16) float hs[4][HIDDEN];
    int d = threadIdx.x;
    int r0 = blockIdx.x * 4;
    if (d < 32) { int rr = d >> 3, cc = d & 7; xs[rr][cc] = x[(size_t)sel[r0 + rr] * 8 + cc]; }
    __syncthreads();
    {
        float wn[8];
        #pragma unroll
        for (int c = 0; c < 8; c++) wn[c] = Wn[c * HIDDEN + d];
        float b = bn[d];
        #pragma unroll
        for (int r = 0; r < 4; r++) {
            float a = b;
            #pragma unroll
            for (int c = 0; c < 8; c++) a = fmaf(xs[r][c], wn[c], a);
            hs[r][d] = a;
        }
    }
    __syncthreads();
    int hh = d >> 4, dd = d & 15;
    float acc[4];
    // Q (pre-scaled by log2(e)/4, split hi/lo)
    proj4(hs, Wq, bq[d], d, acc);
    #pragma unroll
    for (int r = 0; r < 4; r++) {
        float val = acc[r] * 0.36067376022224085f;
        unsigned short hi = f2bf(val);
        unsigned short lo = f2bf(val - bf2f(hi));
        size_t idx = ((size_t)(hh * KSEL) + r0 + r) * 32 + dd;
        qpk[idx] = hi; qpk[idx + 16] = lo;
    }
    // K
    proj4(hs, Wk, bk[d], d, acc);
    #pragma unroll
    for (int r = 0; r < 4; r++) {
        float val = acc[r];
        unsigned short hi = f2bf(val);
        unsigned short lo = f2bf(val - bf2f(hi));
        size_t idx = ((size_t)(hh * KSEL) + r0 + r) * 32 + dd;
        kpk[idx] = hi; kpk[idx + 16] = lo;
    }
    // V (fp32, row-major [q][128])
    proj4(hs, Wv, bv[d], d, acc);
    #pragma unroll
    for (int r = 0; r < 4; r++) vg[(size_t)(r0+r)*HIDDEN + d] = acc[r];
}

// ---- 5. phase 1: row sums l_q via MFMA; chunked LDS (256 rows, 80B stride) ----
__global__ void __launch_bounds__(256) k_attn_l(
        const unsigned short* __restrict__ qpk, const unsigned short* __restrict__ kpk,
        float* __restrict__ lp) {
    __shared__ unsigned short smem[256 * 40];
    int tid = threadIdx.x;
    int ks = blockIdx.x, yg = blockIdx.y, h = blockIdx.z;
    size_t hb = (size_t)h * KSEL;
    int lane = tid & 63, w = tid >> 6;
    int n = lane & 15, g = lane >> 4;
    int q0w = yg * 64 + w * 16;
    bf16x8 afrag = *(const bf16x8*)(qpk + (hb + q0w + n) * 32 + g * 8); // A=[Qh|Ql]
    float l0 = 0.f, l1 = 0.f, l2 = 0.f, l3 = 0.f;
    int b1off = (g & 1) * 8;
    int b2off = 16 + g * 8;
    for (int kc = 0; kc < 4; kc++) {
        __syncthreads();
        {
            int krow = ks * 1024 + kc * 256 + tid;
            const float4* src = (const float4*)(kpk + (hb + krow) * 32);
            float4 a0 = src[0], a1 = src[1], a2 = src[2], a3 = src[3];
            float4* dst = (float4*)&smem[tid * 40];
            dst[0] = a0; dst[1] = a1; dst[2] = a2; dst[3] = a3;
        }
        __syncthreads();
        #pragma unroll 4
        for (int t = 0; t < 16; t++) {
            const unsigned short* rowp = &smem[(t * 16 + n) * 40];
            bf16x8 b1 = *(const bf16x8*)(rowp + b1off);            // [Kh|Kh]
            bf16x8 b2 = {0,0,0,0,0,0,0,0};                          // [Kl|0]
            if (g < 2) b2 = *(const bf16x8*)(rowp + b2off);
            f32x4 c = {0.f, 0.f, 0.f, 0.f};
            c = __builtin_amdgcn_mfma_f32_16x16x32_bf16(afrag, b1, c, 0, 0, 0);
            c = __builtin_amdgcn_mfma_f32_16x16x32_bf16(afrag, b2, c, 0, 0, 0);
            l0 += E2(c[0]); l1 += E2(c[1]); l2 += E2(c[2]); l3 += E2(c[3]);
        }
    }
    #pragma unroll
    for (int m = 1; m < 16; m <<= 1) {
        l0 += __shfl_xor(l0, m); l1 += __shfl_xor(l1, m);
        l2 += __shfl_xor(l2, m); l3 += __shfl_xor(l3, m);
    }
    if (n == 0) {
        size_t base = (hb + q0w + g * 4) * NSLICE + ks;
        lp[base]            = l0; lp[base + NSLICE]     = l1;
        lp[base + 2*NSLICE] = l2; lp[base + 3*NSLICE]   = l3;
    }
}

// ---- 6. combine l partials -> 1/l ----
__global__ void k_rl(const float* __restrict__ lp, float* __restrict__ rl) {
    int i = blockIdx.x * 256 + threadIdx.x;
    float4 p = ((const float4*)lp)[i];
    rl[i] = 1.0f / ((p.x + p.y) + (p.z + p.w));
}

// ---- 7. phase 2: column weights w_j = sum_q exp(s)/l_q (A = K-row [Kh|Kl]) ----
__global__ void __launch_bounds__(256) k_attn_w(
        const unsigned short* __restrict__ qpk, const unsigned short* __restrict__ kpk,
        const float* __restrict__ rl, float* __restrict__ wp) {
    __shared__ unsigned short smem[256 * 40];
    __shared__ float rls[256];
    int tid = threadIdx.x;
    int qs = blockIdx.x, yg = blockIdx.y, h = blockIdx.z;
    size_t hb = (size_t)h * KSEL;
    int lane = tid & 63, w = tid >> 6;
    int n = lane & 15, g = lane >> 4;
    int j0w = yg * 64 + w * 16;
    bf16x8 afrag = *(const bf16x8*)(kpk + (hb + j0w + n) * 32 + g * 8); // A=[Kh|Kl]
    float w0 = 0.f, w1 = 0.f, w2 = 0.f, w3 = 0.f;
    int b1off = (g & 1) * 8;
    int b2off = 16 + g * 8;
    for (int qc = 0; qc < 4; qc++) {
        __syncthreads();
        {
            int qrow = qs * 1024 + qc * 256 + tid;
            const float4* src = (const float4*)(qpk + (hb + qrow) * 32);
            float4 a0 = src[0], a1 = src[1], a2 = src[2], a3 = src[3];
            float4* dst = (float4*)&smem[tid * 40];
            dst[0] = a0; dst[1] = a1; dst[2] = a2; dst[3] = a3;
            rls[tid] = rl[hb + qrow];
        }
        __syncthreads();
        #pragma unroll 4
        for (int t = 0; t < 16; t++) {
            const unsigned short* rowp = &smem[(t * 16 + n) * 40];
            bf16x8 b1 = *(const bf16x8*)(rowp + b1off);            // [Qh|Qh]
            bf16x8 b2 = {0,0,0,0,0,0,0,0};                          // [Ql|0]
            if (g < 2) b2 = *(const bf16x8*)(rowp + b2off);
            f32x4 c = {0.f, 0.f, 0.f, 0.f};
            c = __builtin_amdgcn_mfma_f32_16x16x32_bf16(afrag, b1, c, 0, 0, 0);
            c = __builtin_amdgcn_mfma_f32_16x16x32_bf16(afrag, b2, c, 0, 0, 0);
            float rv = rls[t * 16 + n];
            w0 = fmaf(E2(c[0]), rv, w0); w1 = fmaf(E2(c[1]), rv, w1);
            w2 = fmaf(E2(c[2]), rv, w2); w3 = fmaf(E2(c[3]), rv, w3);
        }
    }
    #pragma unroll
    for (int m = 1; m < 16; m <<= 1) {
        w0 += __shfl_xor(w0, m); w1 += __shfl_xor(w1, m);
        w2 += __shfl_xor(w2, m); w3 += __shfl_xor(w3, m);
    }
    if (n == 0) {
        size_t base = (hb + j0w + g * 4) * NSLICE + qs;
        wp[base]            = w0; wp[base + NSLICE]     = w1;
        wp[base + 2*NSLICE] = w2; wp[base + 3*NSLICE]   = w3;
    }
}

// ---- 8. pooled_av[d] += (1/K) sum_j w[h(d)][j] * v[j][d] ----
__global__ void __launch_bounds__(256) k_colsum(const float* __restrict__ wp, const float* __restrict__ vg,
                                                float* __restrict__ pav) {
    __shared__ float wl[NHEADS][128];
    __shared__ float red[128];
    int tid = threadIdx.x;
    int jb = blockIdx.x * 128;
    for (int i = tid; i < NHEADS * 128; i += 256) {
        int h = i >> 7, jl = i & 127;
        float4 p = ((const float4*)wp)[(size_t)h * KSEL + jb + jl];
        wl[h][jl] = (p.x + p.y) + (p.z + p.w);
    }
    __syncthreads();
    int d = tid & 127, g = tid >> 7;
    int h = d >> 4;
    float acc = 0.f;
    for (int jl = g * 64; jl < g * 64 + 64; jl++)
        acc = fmaf(wl[h][jl], vg[(size_t)(jb + jl) * HIDDEN + d], acc);
    if (g == 1) red[d] = acc;
    __syncthreads();
    if (g == 0) atomicAdd(&pav[d], (acc + red[d]) * (1.0f / (float)KSEL));
}

// ---- 9. out-proj + pool MLP ----
__global__ void __launch_bounds__(256) k_final(const float* __restrict__ pav,
        const float* __restrict__ Wo, const float* __restrict__ bo,
        const float* __restrict__ W1, const float* __restrict__ b1,
        const float* __restrict__ W2, const float* __restrict__ b2,
        float* __restrict__ out) {
    __shared__ float sp[HIDDEN];
    __shared__ float st[OUTD];
    int t = threadIdx.x;
    if (t < HIDDEN) {
        float a = bo[t];
        for (int c = 0; c < HIDDEN; c++) a = fmaf(pav[c], Wo[c * HIDDEN + t], a);
        sp[t] = a;
    }
    __syncthreads();
    {
        float a = b1[t];
        for (int c = 0; c < HIDDEN; c++) a = fmaf(sp[c], W1[c * OUTD + t], a);
        st[t] = fmaxf(a, 0.f);
    }
    __syncthreads();
    {
        float o = b2[t];
        for (int c = 0; c < OUTD; c++) o = fmaf(st[c], W2[c * OUTD + t], o);
        out[t] = o;
    }
}

extern "C" void kernel_launch(void* const* d_in, const int* in_sizes, int n_in,
                              void* d_out, int out_size, void* d_ws, size_t ws_size,
                              hipStream_t stream) {
    (void)n_in; (void)out_size; (void)ws_size;
    const float* x   = (const float*)d_in[0];
    const float* pos = (const float*)d_in[1];
    const float* lig = (const float*)d_in[2];
    const float* Wn  = (const float*)d_in[3];
    const float* bn  = (const float*)d_in[4];
    const float* Wq  = (const float*)d_in[5];
    const float* bq  = (const float*)d_in[6];
    const float* Wk  = (const float*)d_in[7];
    const float* bk  = (const float*)d_in[8];
    const float* Wv  = (const float*)d_in[9];
    const float* bv  = (const float*)d_in[10];
    const float* Wo  = (const float*)d_in[11];
    const float* bo  = (const float*)d_in[12];
    const float* W1  = (const float*)d_in[13];
    const float* b1  = (const float*)d_in[14];
    const float* W2  = (const float*)d_in[15];
    const float* b2  = (const float*)d_in[16];
    int M = in_sizes[2] / 3;

    char* ws = (char*)d_ws;
    unsigned short* pa  = (unsigned short*)(ws + OFF_PA);
    unsigned short* pb  = (unsigned short*)(ws + OFF_PB);
    float*          sq  = (float*)(ws + OFF_SQ);
    float*          dl  = (float*)(ws + OFF_DL);
    int*            cnt = (int*)  (ws + OFF_CNT);
    unsigned int*   nfl = (unsigned int*)(ws + OFF_NFLAG);
    unsigned int*   flg = (unsigned int*)(ws + OFF_FLG);
    int*            sel = (int*)  (ws + OFF_SEL);
    unsigned short* qpk = (unsigned short*)(ws + OFF_QPK);
    unsigned short* kpk = (unsigned short*)(ws + OFF_KPK);
    float*          vg  = (float*)(ws + OFF_V);
    float*          lp  = (float*)(ws + OFF_LP);
    float*          rl  = (float*)(ws + OFF_RL);
    float*          wp  = (float*)(ws + OFF_WP);
    float*          pav = (float*)(ws + OFF_PAV);

    hipMemsetAsync(ws + OFF_CNT, 0, (size_t)NPTS * 4 + 1024, stream);  // cnt + nflag
    hipMemsetAsync(ws + OFF_PAV, 0, (size_t)HIDDEN * 4, stream);

    hipLaunchKernelGGL(k_prep,     dim3(64),       dim3(256),  0, stream, pos, lig, M, pa, pb, sq, dl);
    hipLaunchKernelGGL(k_neighbor, dim3(256, 8),   dim3(256),  0, stream, pa, pb, cnt, flg, nfl);
    hipLaunchKernelGGL(k_fixup,    dim3(32),       dim3(256),  0, stream, pos, sq, flg, nfl, cnt);
    hipLaunchKernelGGL(k_select,   dim3(1),        dim3(1024), 0, stream, dl, cnt, sel);
    hipLaunchKernelGGL(k_qkv,      dim3(KSEL/4),   dim3(128),  0, stream, x, sel, Wn, bn, Wq, bq, Wk, bk, Wv, bv, qpk, kpk, vg);
    hipLaunchKernelGGL(k_attn_l,   dim3(4, 64, 8), dim3(256),  0, stream, qpk, kpk, lp);
    hipLaunchKernelGGL(k_rl,       dim3(NHEADS*KSEL/256), dim3(256), 0, stream, lp, rl);
    hipLaunchKernelGGL(k_attn_w,   dim3(4, 64, 8), dim3(256),  0, stream, qpk, kpk, rl, wp);
    hipLaunchKernelGGL(k_colsum,   dim3(32),       dim3(256),  0, stream, wp, vg, pav);
    hipLaunchKernelGGL(k_final,    dim3(1),        dim3(256),  0, stream, pav, Wo, bo, W1, b1, W2, b2, (float*)d_out);
}

// Round 9
// 289.191 us; speedup vs baseline: 1.7507x; 1.0179x over previous
//
#include <hip/hip_runtime.h>
#include <cstdint>
#include <cstddef>

#define NPTS 16384
#define KSEL 4096
#define HIDDEN 128
#define NHEADS 8
#define DHEAD 16
#define OUTD 256
#define NSLICE 4   // k/q slices for attn partials
#define FCAP 131072
#define LCAP 2048
#define TAU 0.2f

typedef __attribute__((ext_vector_type(8))) short bf16x8;
typedef __attribute__((ext_vector_type(4))) float f32x4;
typedef __attribute__((ext_vector_type(16))) float f32x16;

#if defined(__has_builtin)
#if __has_builtin(__builtin_amdgcn_exp2f)
#define E2(x) __builtin_amdgcn_exp2f(x)
#endif
#endif
#ifndef E2
#define E2(x) exp2f(x)
#endif

// ---- workspace layout (bytes) ----
constexpr size_t OFF_PA    = 1024;                         // NPTS*16 bf16 (A-side packed)
constexpr size_t OFF_PB    = OFF_PA  + (size_t)NPTS*32;    // NPTS*16 bf16 (B-side packed)
constexpr size_t OFF_SQ    = OFF_PB  + (size_t)NPTS*32;
constexpr size_t OFF_DL    = OFF_SQ  + (size_t)NPTS*4;
constexpr size_t OFF_CNT   = OFF_DL  + (size_t)NPTS*4;     // int (memset 0)
constexpr size_t OFF_NFLAG = OFF_CNT + (size_t)NPTS*4;     // uint (memset 0, padded 1KB)
constexpr size_t OFF_FLG   = OFF_NFLAG + 1024;             // FCAP uints
constexpr size_t OFF_SEL   = OFF_FLG + (size_t)FCAP*4;     // KSEL int
constexpr size_t SZ_PK     = (size_t)NHEADS*KSEL*32*2;     // 2 MB packed [hi16|lo16] bf16
constexpr size_t OFF_QPK   = OFF_SEL + (size_t)KSEL*4;
constexpr size_t OFF_KPK   = OFF_QPK + SZ_PK;
constexpr size_t OFF_V     = OFF_KPK + SZ_PK;                      // KSEL*128 f32
constexpr size_t OFF_LP    = OFF_V  + (size_t)KSEL*HIDDEN*4;       // 8*4096*4 f32 partial l
constexpr size_t OFF_RL    = OFF_LP + (size_t)NHEADS*KSEL*NSLICE*4; // 8*4096 f32 1/l
constexpr size_t OFF_WP    = OFF_RL + (size_t)NHEADS*KSEL*4;        // 8*4096*4 f32 partial w
constexpr size_t OFF_PAV   = OFF_WP + (size_t)NHEADS*KSEL*NSLICE*4; // 128 f32

__device__ __forceinline__ unsigned short f2bf(float f) {
    union { float f; unsigned u; } v; v.f = f;
    unsigned r = v.u + 0x7fffu + ((v.u >> 16) & 1u);
    return (unsigned short)(r >> 16);
}
__device__ __forceinline__ float bf2f(unsigned short h) {
    union { unsigned u; float f; } v; v.u = ((unsigned)h) << 16;
    return v.f;
}

// ---- 1. prep: ligand center, sq, d_lig, packed hi/lo coords (+sq split) for MFMA d2 ----
__global__ void __launch_bounds__(256) k_prep(const float* __restrict__ pos, const float* __restrict__ lig, int M,
                       unsigned short* __restrict__ pa, unsigned short* __restrict__ pb,
                       float* __restrict__ sq, float* __restrict__ dl) {
    __shared__ float ls[128];
    __shared__ float ctr[3];
    int tid = threadIdx.x;
    for (int i = tid; i < 3 * M; i += 256) ls[i] = lig[i];
    __syncthreads();
    if (tid < 3) {
        float s = 0.f;
        for (int i = 0; i < M; i++) s += ls[i * 3 + tid];
        ctr[tid] = s / (float)M;
    }
    __syncthreads();
    int i = blockIdx.x * 256 + tid;
    float x = pos[i*3+0], y = pos[i*3+1], z = pos[i*3+2];
    float s = (x*x + y*y) + z*z;
    sq[i] = s;
    float dx = x - ctr[0], dy = y - ctr[1], dz = z - ctr[2];
    dl[i] = sqrtf((dx*dx + dy*dy) + dz*dz);
    unsigned short xh = f2bf(x); float xr = bf2f(xh); float xl = x - xr;
    unsigned short yh = f2bf(y); float yr = bf2f(yh); float yl = y - yr;
    unsigned short zh = f2bf(z); float zr = bf2f(zh); float zl = z - zr;
    unsigned short xlb = f2bf(xl), ylb = f2bf(yl), zlb = f2bf(zl);
    unsigned short xhA = f2bf(-2.f*xr), xlA = f2bf(-2.f*xl);
    unsigned short yhA = f2bf(-2.f*yr), ylA = f2bf(-2.f*yl);
    unsigned short zhA = f2bf(-2.f*zr), zlA = f2bf(-2.f*zl);
    unsigned short sih = f2bf(s);
    unsigned short sil = f2bf(s - bf2f(sih));
    unsigned short one = f2bf(1.0f);
    union { unsigned short s[16]; float4 f[2]; } A, B;
    // k-slots: per coord (hh, h*lo_j, lo_i*h), 9-11 lo*lo, 12-13 s_a*1, 14-15 1*s_b
    A.s[0]=xhA; A.s[1]=xhA; A.s[2]=xlA;
    A.s[3]=yhA; A.s[4]=yhA; A.s[5]=ylA;
    A.s[6]=zhA; A.s[7]=zhA; A.s[8]=zlA;
    A.s[9]=xlA; A.s[10]=ylA; A.s[11]=zlA;
    A.s[12]=sih; A.s[13]=sil; A.s[14]=one; A.s[15]=one;
    B.s[0]=xh;  B.s[1]=xlb;  B.s[2]=xh;
    B.s[3]=yh;  B.s[4]=ylb;  B.s[5]=yh;
    B.s[6]=zh;  B.s[7]=zlb;  B.s[8]=zh;
    B.s[9]=xlb; B.s[10]=ylb; B.s[11]=zlb;
    B.s[12]=one; B.s[13]=one; B.s[14]=sih; B.s[15]=sil;
    float4* pad = (float4*)(pa + (size_t)i * 16);
    pad[0] = A.f[0]; pad[1] = A.f[1];
    float4* pbd = (float4*)(pb + (size_t)i * 16);
    pbd[0] = B.f[0]; pbd[1] = B.f[1];
}

// ---- 2. neighbor counts via ONE 32x32x16 MFMA per 1024 pairs ----
// A = pa[j-tile] (LDS), B = pb[i-rows] (regs, fixed per wave). C col=lane&31 -> i fixed
// per lane: accumulate row-count in a scalar register across all tiles; no shuffles.
// grid (128, 8), block 256 = 4 waves x 32 i-rows
__global__ void __launch_bounds__(256) k_neighbor(
        const unsigned short* __restrict__ pa, const unsigned short* __restrict__ pb,
        int* __restrict__ cnt, unsigned int* __restrict__ flg, unsigned int* __restrict__ nflag) {
    __shared__ unsigned short js[256 * 24];     // 48B row stride (16B-aligned halves)
    __shared__ unsigned int fbuf[LCAP];
    __shared__ unsigned int fcnt, fbase;
    int tid = threadIdx.x;
    if (tid == 0) fcnt = 0;
    int lane = tid & 63, w = tid >> 6;
    int half = lane >> 5, il = lane & 31;
    int i = blockIdx.x * 128 + w * 32 + il;
    bf16x8 bfrag = *(const bf16x8*)(pb + (size_t)i * 16 + half * 8);
    int jb0 = blockIdx.y * 2048;
    int acc = 0;
    for (int chv = 0; chv < 8; chv++) {
        int jb = jb0 + chv * 256;
        __syncthreads();
        {
            const float4* src = (const float4*)(pa + (size_t)(jb + tid) * 16);
            float4 v0 = src[0], v1 = src[1];
            float4* dst = (float4*)&js[tid * 24];
            dst[0] = v0; dst[1] = v1;
        }
        __syncthreads();
        #pragma unroll 2
        for (int t = 0; t < 8; t++) {
            bf16x8 afrag = *(const bf16x8*)&js[(t * 32 + il) * 24 + half * 8];
            f32x16 c = {0.f,0.f,0.f,0.f,0.f,0.f,0.f,0.f,0.f,0.f,0.f,0.f,0.f,0.f,0.f,0.f};
            c = __builtin_amdgcn_mfma_f32_32x32x16_bf16(afrag, bfrag, c, 0, 0, 0);
            int cs = 0, cl = 0;
            #pragma unroll
            for (int r = 0; r < 16; r++) {
                cs += (c[r] < 9.0f - TAU);
                cl += (c[r] < 9.0f + TAU);
            }
            acc += cs;
            if (cl != cs) {                  // rare: boundary pair(s) in this lane's column
                int jt = jb + t * 32;
                #pragma unroll
                for (int r = 0; r < 16; r++) {
                    float d = c[r];
                    if (d < 9.0f + TAU && d >= 9.0f - TAU) {
                        int j = jt + (r & 3) + 8 * (r >> 2) + 4 * half;
                        unsigned xx = atomicAdd(&fcnt, 1u);
                        if (xx < LCAP) fbuf[xx] = ((unsigned)i << 14) | (unsigned)j;
                    }
                }
            }
        }
    }
    acc += __shfl_xor(acc, 32);
    if (half == 0) atomicAdd(&cnt[i], acc);
    __syncthreads();
    if (tid == 0) {
        unsigned cf = fcnt; if (cf > LCAP) cf = LCAP;
        fcnt = cf;
        fbase = atomicAdd(nflag, cf);
    }
    __syncthreads();
    unsigned cf = fcnt, fb = fbase;
    for (unsigned xx = tid; xx < cf; xx += 256) {
        unsigned di = fb + xx;
        if (di < FCAP) flg[di] = fbuf[xx];
    }
}

// ---- 2b. resolve boundary-window pairs exactly (fp32) ----
__global__ void __launch_bounds__(256) k_fixup(const float* __restrict__ pos, const float* __restrict__ sq,
        const unsigned int* __restrict__ flg, const unsigned int* __restrict__ nflag,
        int* __restrict__ cnt) {
    int nf = (int)*nflag; if (nf > FCAP) nf = FCAP;
    for (int idx = blockIdx.x * 256 + threadIdx.x; idx < nf; idx += gridDim.x * 256) {
        unsigned pr = flg[idx];
        int i = (int)((pr >> 14) & 16383u), j = (int)(pr & 16383u);
        float xi = pos[i*3+0], yi = pos[i*3+1], zi = pos[i*3+2];
        float xj = pos[j*3+0], yj = pos[j*3+1], zj = pos[j*3+2];
        float dot = fmaf(xi, xj, fmaf(yi, yj, zi * zj));
        float d2 = (sq[i] + sq[j]) - 2.0f * dot;
        if (d2 < 9.0f) atomicAdd(&cnt[i], 1);
    }
}

// ---- 3. scores (fused) + exact top-KSEL radix select (parallel suffix scan) ----
__global__ void __launch_bounds__(1024) k_select(const float* __restrict__ dl, const int* __restrict__ cnt,
                                                 int* __restrict__ sel) {
    __shared__ unsigned int sk[NPTS];
    __shared__ int hist[256];
    __shared__ int scan2[256];
    __shared__ unsigned int s_prefix;
    __shared__ int s_rem, s_eqtot, s_nout, s_digit, s_cgt;
    int tid = threadIdx.x;
    for (int i = tid; i < NPTS; i += 1024) {
        float score = 1.0f / (1.0f + dl[i] / 5.0f) + 0.5f * (1.0f / (float)cnt[i]);
        unsigned int u = __float_as_uint(score);
        sk[i] = u ^ ((u & 0x80000000u) ? 0xFFFFFFFFu : 0x80000000u);
    }
    if (tid == 0) { s_prefix = 0; s_rem = KSEL; s_nout = 0; s_eqtot = 0; }
    __syncthreads();
    for (int p = 0; p < 4; p++) {
        int sh = 24 - 8 * p;
        if (tid < 256) hist[tid] = 0;
        __syncthreads();
        unsigned int pref = s_prefix;
        int shp = (p == 0) ? 0 : (32 - 8 * p);
        for (int i = tid; i < NPTS; i += 1024) {
            unsigned int key = sk[i];
            bool m = (p == 0) || ((key >> shp) == pref);
            if (m) atomicAdd(&hist[(key >> sh) & 255], 1);
        }
        __syncthreads();
        if (tid < 256) scan2[tid] = hist[tid];
        __syncthreads();
        for (int off = 1; off < 256; off <<= 1) {
            int v = 0;
            if (tid < 256) { v = scan2[tid]; if (tid + off < 256) v += scan2[tid + off]; }
            __syncthreads();
            if (tid < 256) scan2[tid] = v;
            __syncthreads();
        }
        int rem = s_rem;
        if (tid < 256) {
            int hi = scan2[tid];
            int lo = hi - hist[tid];
            if (hi >= rem && lo < rem) { s_digit = tid; s_cgt = lo; }
        }
        __syncthreads();
        if (tid == 0) {
            s_prefix = (s_prefix << 8) | (unsigned int)s_digit;
            s_rem = rem - s_cgt;
            if (p == 3) s_eqtot = hist[s_digit];
        }
        __syncthreads();
    }
    unsigned int T = s_prefix;
    int need_eq = s_rem;
    for (int i = tid; i < NPTS; i += 1024)
        if (sk[i] > T) sel[atomicAdd(&s_nout, 1)] = i;
    __syncthreads();
    if (s_eqtot == need_eq) {
        for (int i = tid; i < NPTS; i += 1024)
            if (sk[i] == T) sel[atomicAdd(&s_nout, 1)] = i;
    } else {
        for (int i = tid; i < NPTS; i += 1024) {
            if (sk[i] == T) {
                int rank = 0;
                for (int j = 0; j < i; j++) rank += (sk[j] == T);
                if (rank < need_eq) sel[atomicAdd(&s_nout, 1)] = i;
            }
        }
    }
}

// ---- 4. gather + node embed + QKV projections (4 rows/block for 2 waves/SIMD) ----
__device__ __forceinline__ void proj4(const float hs[4][HIDDEN], const float* __restrict__ W,
                                      float b, int d, float* acc) {
    #pragma unroll
    for (int r = 0; r < 4; r++) acc[r] = b;
    for (int c = 0; c < HIDDEN; c += 4) {
        float w0 = W[(c+0)*HIDDEN+d], w1 = W[(c+1)*HIDDEN+d], w2 = W[(c+2)*HIDDEN+d], w3 = W[(c+3)*HIDDEN+d];
        #pragma unroll
        for (int r = 0; r < 4; r++) {
            float4 h4 = *(const float4*)&hs[r][c];
            float a = acc[r];
            a = fmaf(h4.x, w0, a); a = fmaf(h4.y, w1, a); a = fmaf(h4.z, w2, a); a = fmaf(h4.w, w3, a);
            acc[r] = a;
        }
    }
}

__global__ void __launch_bounds__(128) k_qkv(const float* __restrict__ x, const int* __restrict__ sel,
        const float* __restrict__ Wn, const float* __restrict__ bn,
        const float* __restrict__ Wq, const float* __restrict__ bq,
        const float* __restrict__ Wk, const float* __restrict__ bk,
        const float* __restrict__ Wv, const float* __restrict__ bv,
        unsigned short* __restrict__ qpk, unsigned short* __restrict__ kpk,
        float* __restrict__ vg) {
    __shared__ float xs[4][8];
    __shared__ __align__(16) float hs[4][HIDDEN];
    int d = threadIdx.x;
    int r0 = blockIdx.x * 4;
    if (d < 32) { int rr = d >> 3, cc = d & 7; xs[rr][cc] = x[(size_t)sel[r0 + rr] * 8 + cc]; }
    __syncthreads();
    {
        float wn[8];
        #pragma unroll
        for (int c = 0; c < 8; c++) wn[c] = Wn[c * HIDDEN + d];
        float b = bn[d];
        #pragma unroll
        for (int r = 0; r < 4; r++) {
            float a = b;
            #pragma unroll
            for (int c = 0; c < 8; c++) a = fmaf(xs[r][c], wn[c], a);
            hs[r][d] = a;
        }
    }
    __syncthreads();
    int hh = d >> 4, dd = d & 15;
    float acc[4];
    // Q (pre-scaled by log2(e)/4, split hi/lo)
    proj4(hs, Wq, bq[d], d, acc);
    #pragma unroll
    for (int r = 0; r < 4; r++) {
        float val = acc[r] * 0.36067376022224085f;
        unsigned short hi = f2bf(val);
        unsigned short lo = f2bf(val - bf2f(hi));
        size_t idx = ((size_t)(hh * KSEL) + r0 + r) * 32 + dd;
        qpk[idx] = hi; qpk[idx + 16] = lo;
    }
    // K
    proj4(hs, Wk, bk[d], d, acc);
    #pragma unroll
    for (int r = 0; r < 4; r++) {
        float val = acc[r];
        unsigned short hi = f2bf(val);
        unsigned short lo = f2bf(val - bf2f(hi));
        size_t idx = ((size_t)(hh * KSEL) + r0 + r) * 32 + dd;
        kpk[idx] = hi; kpk[idx + 16] = lo;
    }
    // V (fp32, row-major [q][128])
    proj4(hs, Wv, bv[d], d, acc);
    #pragma unroll
    for (int r = 0; r < 4; r++) vg[(size_t)(r0+r)*HIDDEN + d] = acc[r];
}

// ---- 5. phase 1: row sums l_q via MFMA; chunked LDS (256 rows, 80B stride) ----
__global__ void __launch_bounds__(256) k_attn_l(
        const unsigned short* __restrict__ qpk, const unsigned short* __restrict__ kpk,
        float* __restrict__ lp) {
    __shared__ unsigned short smem[256 * 40];
    int tid = threadIdx.x;
    int ks = blockIdx.x, yg = blockIdx.y, h = blockIdx.z;
    size_t hb = (size_t)h * KSEL;
    int lane = tid & 63, w = tid >> 6;
    int n = lane & 15, g = lane >> 4;
    int q0w = yg * 64 + w * 16;
    bf16x8 afrag = *(const bf16x8*)(qpk + (hb + q0w + n) * 32 + g * 8); // A=[Qh|Ql]
    float l0 = 0.f, l1 = 0.f, l2 = 0.f, l3 = 0.f;
    int b1off = (g & 1) * 8;
    int b2off = 16 + g * 8;
    for (int kc = 0; kc < 4; kc++) {
        __syncthreads();
        {
            int krow = ks * 1024 + kc * 256 + tid;
            const float4* src = (const float4*)(kpk + (hb + krow) * 32);
            float4 a0 = src[0], a1 = src[1], a2 = src[2], a3 = src[3];
            float4* dst = (float4*)&smem[tid * 40];
            dst[0] = a0; dst[1] = a1; dst[2] = a2; dst[3] = a3;
        }
        __syncthreads();
        #pragma unroll 4
        for (int t = 0; t < 16; t++) {
            const unsigned short* rowp = &smem[(t * 16 + n) * 40];
            bf16x8 b1 = *(const bf16x8*)(rowp + b1off);            // [Kh|Kh]
            bf16x8 b2 = {0,0,0,0,0,0,0,0};                          // [Kl|0]
            if (g < 2) b2 = *(const bf16x8*)(rowp + b2off);
            f32x4 c = {0.f, 0.f, 0.f, 0.f};
            c = __builtin_amdgcn_mfma_f32_16x16x32_bf16(afrag, b1, c, 0, 0, 0);
            c = __builtin_amdgcn_mfma_f32_16x16x32_bf16(afrag, b2, c, 0, 0, 0);
            l0 += E2(c[0]); l1 += E2(c[1]); l2 += E2(c[2]); l3 += E2(c[3]);
        }
    }
    #pragma unroll
    for (int m = 1; m < 16; m <<= 1) {
        l0 += __shfl_xor(l0, m); l1 += __shfl_xor(l1, m);
        l2 += __shfl_xor(l2, m); l3 += __shfl_xor(l3, m);
    }
    if (n == 0) {
        size_t base = (hb + q0w + g * 4) * NSLICE + ks;
        lp[base]            = l0; lp[base + NSLICE]     = l1;
        lp[base + 2*NSLICE] = l2; lp[base + 3*NSLICE]   = l3;
    }
}

// ---- 6. combine l partials -> 1/l ----
__global__ void k_rl(const float* __restrict__ lp, float* __restrict__ rl) {
    int i = blockIdx.x * 256 + threadIdx.x;
    float4 p = ((const float4*)lp)[i];
    rl[i] = 1.0f / ((p.x + p.y) + (p.z + p.w));
}

// ---- 7. phase 2: column weights w_j = sum_q exp(s)/l_q (A = K-row [Kh|Kl]) ----
__global__ void __launch_bounds__(256) k_attn_w(
        const unsigned short* __restrict__ qpk, const unsigned short* __restrict__ kpk,
        const float* __restrict__ rl, float* __restrict__ wp) {
    __shared__ unsigned short smem[256 * 40];
    __shared__ float rls[256];
    int tid = threadIdx.x;
    int qs = blockIdx.x, yg = blockIdx.y, h = blockIdx.z;
    size_t hb = (size_t)h * KSEL;
    int lane = tid & 63, w = tid >> 6;
    int n = lane & 15, g = lane >> 4;
    int j0w = yg * 64 + w * 16;
    bf16x8 afrag = *(const bf16x8*)(kpk + (hb + j0w + n) * 32 + g * 8); // A=[Kh|Kl]
    float w0 = 0.f, w1 = 0.f, w2 = 0.f, w3 = 0.f;
    int b1off = (g & 1) * 8;
    int b2off = 16 + g * 8;
    for (int qc = 0; qc < 4; qc++) {
        __syncthreads();
        {
            int qrow = qs * 1024 + qc * 256 + tid;
            const float4* src = (const float4*)(qpk + (hb + qrow) * 32);
            float4 a0 = src[0], a1 = src[1], a2 = src[2], a3 = src[3];
            float4* dst = (float4*)&smem[tid * 40];
            dst[0] = a0; dst[1] = a1; dst[2] = a2; dst[3] = a3;
            rls[tid] = rl[hb + qrow];
        }
        __syncthreads();
        #pragma unroll 4
        for (int t = 0; t < 16; t++) {
            const unsigned short* rowp = &smem[(t * 16 + n) * 40];
            bf16x8 b1 = *(const bf16x8*)(rowp + b1off);            // [Qh|Qh]
            bf16x8 b2 = {0,0,0,0,0,0,0,0};                          // [Ql|0]
            if (g < 2) b2 = *(const bf16x8*)(rowp + b2off);
            f32x4 c = {0.f, 0.f, 0.f, 0.f};
            c = __builtin_amdgcn_mfma_f32_16x16x32_bf16(afrag, b1, c, 0, 0, 0);
            c = __builtin_amdgcn_mfma_f32_16x16x32_bf16(afrag, b2, c, 0, 0, 0);
            float rv = rls[t * 16 + n];
            w0 = fmaf(E2(c[0]), rv, w0); w1 = fmaf(E2(c[1]), rv, w1);
            w2 = fmaf(E2(c[2]), rv, w2); w3 = fmaf(E2(c[3]), rv, w3);
        }
    }
    #pragma unroll
    for (int m = 1; m < 16; m <<= 1) {
        w0 += __shfl_xor(w0, m); w1 += __shfl_xor(w1, m);
        w2 += __shfl_xor(w2, m); w3 += __shfl_xor(w3, m);
    }
    if (n == 0) {
        size_t base = (hb + j0w + g * 4) * NSLICE + qs;
        wp[base]            = w0; wp[base + NSLICE]     = w1;
        wp[base + 2*NSLICE] = w2; wp[base + 3*NSLICE]   = w3;
    }
}

// ---- 8. pooled_av[d] += (1/K) sum_j w[h(d)][j] * v[j][d] ----
__global__ void __launch_bounds__(256) k_colsum(const float* __restrict__ wp, const float* __restrict__ vg,
                                                float* __restrict__ pav) {
    __shared__ float wl[NHEADS][128];
    __shared__ float red[128];
    int tid = threadIdx.x;
    int jb = blockIdx.x * 128;
    for (int i = tid; i < NHEADS * 128; i += 256) {
        int h = i >> 7, jl = i & 127;
        float4 p = ((const float4*)wp)[(size_t)h * KSEL + jb + jl];
        wl[h][jl] = (p.x + p.y) + (p.z + p.w);
    }
    __syncthreads();
    int d = tid & 127, g = tid >> 7;
    int h = d >> 4;
    float acc = 0.f;
    for (int jl = g * 64; jl < g * 64 + 64; jl++)
        acc = fmaf(wl[h][jl], vg[(size_t)(jb + jl) * HIDDEN + d], acc);
    if (g == 1) red[d] = acc;
    __syncthreads();
    if (g == 0) atomicAdd(&pav[d], (acc + red[d]) * (1.0f / (float)KSEL));
}

// ---- 9. out-proj + pool MLP ----
__global__ void __launch_bounds__(256) k_final(const float* __restrict__ pav,
        const float* __restrict__ Wo, const float* __restrict__ bo,
        const float* __restrict__ W1, const float* __restrict__ b1,
        const float* __restrict__ W2, const float* __restrict__ b2,
        float* __restrict__ out) {
    __shared__ float sp[HIDDEN];
    __shared__ float st[OUTD];
    int t = threadIdx.x;
    if (t < HIDDEN) {
        float a = bo[t];
        for (int c = 0; c < HIDDEN; c++) a = fmaf(pav[c], Wo[c * HIDDEN + t], a);
        sp[t] = a;
    }
    __syncthreads();
    {
        float a = b1[t];
        for (int c = 0; c < HIDDEN; c++) a = fmaf(sp[c], W1[c * OUTD + t], a);
        st[t] = fmaxf(a, 0.f);
    }
    __syncthreads();
    {
        float o = b2[t];
        for (int c = 0; c < OUTD; c++) o = fmaf(st[c], W2[c * OUTD + t], o);
        out[t] = o;
    }
}

extern "C" void kernel_launch(void* const* d_in, const int* in_sizes, int n_in,
                              void* d_out, int out_size, void* d_ws, size_t ws_size,
                              hipStream_t stream) {
    (void)n_in; (void)out_size; (void)ws_size;
    const float* x   = (const float*)d_in[0];
    const float* pos = (const float*)d_in[1];
    const float* lig = (const float*)d_in[2];
    const float* Wn  = (const float*)d_in[3];
    const float* bn  = (const float*)d_in[4];
    const float* Wq  = (const float*)d_in[5];
    const float* bq  = (const float*)d_in[6];
    const float* Wk  = (const float*)d_in[7];
    const float* bk  = (const float*)d_in[8];
    const float* Wv  = (const float*)d_in[9];
    const float* bv  = (const float*)d_in[10];
    const float* Wo  = (const float*)d_in[11];
    const float* bo  = (const float*)d_in[12];
    const float* W1  = (const float*)d_in[13];
    const float* b1  = (const float*)d_in[14];
    const float* W2  = (const float*)d_in[15];
    const float* b2  = (const float*)d_in[16];
    int M = in_sizes[2] / 3;

    char* ws = (char*)d_ws;
    unsigned short* pa  = (unsigned short*)(ws + OFF_PA);
    unsigned short* pb  = (unsigned short*)(ws + OFF_PB);
    float*          sq  = (float*)(ws + OFF_SQ);
    float*          dl  = (float*)(ws + OFF_DL);
    int*            cnt = (int*)  (ws + OFF_CNT);
    unsigned int*   nfl = (unsigned int*)(ws + OFF_NFLAG);
    unsigned int*   flg = (unsigned int*)(ws + OFF_FLG);
    int*            sel = (int*)  (ws + OFF_SEL);
    unsigned short* qpk = (unsigned short*)(ws + OFF_QPK);
    unsigned short* kpk = (unsigned short*)(ws + OFF_KPK);
    float*          vg  = (float*)(ws + OFF_V);
    float*          lp  = (float*)(ws + OFF_LP);
    float*          rl  = (float*)(ws + OFF_RL);
    float*          wp  = (float*)(ws + OFF_WP);
    float*          pav = (float*)(ws + OFF_PAV);

    hipMemsetAsync(ws + OFF_CNT, 0, (size_t)NPTS * 4 + 1024, stream);  // cnt + nflag
    hipMemsetAsync(ws + OFF_PAV, 0, (size_t)HIDDEN * 4, stream);

    hipLaunchKernelGGL(k_prep,     dim3(64),       dim3(256),  0, stream, pos, lig, M, pa, pb, sq, dl);
    hipLaunchKernelGGL(k_neighbor, dim3(128, 8),   dim3(256),  0, stream, pa, pb, cnt, flg, nfl);
    hipLaunchKernelGGL(k_fixup,    dim3(32),       dim3(256),  0, stream, pos, sq, flg, nfl, cnt);
    hipLaunchKernelGGL(k_select,   dim3(1),        dim3(1024), 0, stream, dl, cnt, sel);
    hipLaunchKernelGGL(k_qkv,      dim3(KSEL/4),   dim3(128),  0, stream, x, sel, Wn, bn, Wq, bq, Wk, bk, Wv, bv, qpk, kpk, vg);
    hipLaunchKernelGGL(k_attn_l,   dim3(4, 64, 8), dim3(256),  0, stream, qpk, kpk, lp);
    hipLaunchKernelGGL(k_rl,       dim3(NHEADS*KSEL/256), dim3(256), 0, stream, lp, rl);
    hipLaunchKernelGGL(k_attn_w,   dim3(4, 64, 8), dim3(256),  0, stream, qpk, kpk, rl, wp);
    hipLaunchKernelGGL(k_colsum,   dim3(32),       dim3(256),  0, stream, wp, vg, pav);
    hipLaunchKernelGGL(k_final,    dim3(1),        dim3(256),  0, stream, pav, Wo, bo, W1, b1, W2, b2, (float*)d_out);
}

// Round 10
// 266.431 us; speedup vs baseline: 1.9002x; 1.0854x over previous
//
#include <hip/hip_runtime.h>
#include <cstdint>
#include <cstddef>

#define NPTS 16384
#define KSEL 4096
#define HIDDEN 128
#define NHEADS 8
#define DHEAD 16
#define OUTD 256
#define NSLICE 4   // k/q slices for attn partials
#define FCAP 131072
#define LCAP 2048
#define TAU 0.2f

typedef __attribute__((ext_vector_type(8))) short bf16x8;
typedef __attribute__((ext_vector_type(4))) float f32x4;
typedef __attribute__((ext_vector_type(16))) float f32x16;

#if defined(__has_builtin)
#if __has_builtin(__builtin_amdgcn_exp2f)
#define E2(x) __builtin_amdgcn_exp2f(x)
#endif
#endif
#ifndef E2
#define E2(x) exp2f(x)
#endif

// ---- workspace layout (bytes) ----
constexpr size_t OFF_PA    = 1024;                         // NPTS*16 bf16 (A-side packed)
constexpr size_t OFF_PB    = OFF_PA  + (size_t)NPTS*32;    // NPTS*16 bf16 (B-side packed)
constexpr size_t OFF_SQ    = OFF_PB  + (size_t)NPTS*32;
constexpr size_t OFF_DL    = OFF_SQ  + (size_t)NPTS*4;
constexpr size_t OFF_CNT   = OFF_DL  + (size_t)NPTS*4;     // int (memset 0)
constexpr size_t OFF_NFLAG = OFF_CNT + (size_t)NPTS*4;     // uint (memset 0, padded 1KB)
constexpr size_t OFF_FLG   = OFF_NFLAG + 1024;             // FCAP uints
constexpr size_t OFF_SEL   = OFF_FLG + (size_t)FCAP*4;     // KSEL int
constexpr size_t SZ_PK     = (size_t)NHEADS*KSEL*32*2;     // 2 MB packed [hi16|lo16] bf16
constexpr size_t OFF_QPK   = OFF_SEL + (size_t)KSEL*4;
constexpr size_t OFF_KPK   = OFF_QPK + SZ_PK;
constexpr size_t OFF_V     = OFF_KPK + SZ_PK;                      // KSEL*128 f32
constexpr size_t OFF_LP    = OFF_V  + (size_t)KSEL*HIDDEN*4;       // 8*4096*4 f32 partial l
constexpr size_t OFF_RL    = OFF_LP + (size_t)NHEADS*KSEL*NSLICE*4; // (unused, kept)
constexpr size_t OFF_WP    = OFF_RL + (size_t)NHEADS*KSEL*4;        // 8*4096*4 f32 partial w
constexpr size_t OFF_PAV   = OFF_WP + (size_t)NHEADS*KSEL*NSLICE*4; // 128 f32

__device__ __forceinline__ unsigned short f2bf(float f) {
    union { float f; unsigned u; } v; v.f = f;
    unsigned r = v.u + 0x7fffu + ((v.u >> 16) & 1u);
    return (unsigned short)(r >> 16);
}
__device__ __forceinline__ float bf2f(unsigned short h) {
    union { unsigned u; float f; } v; v.u = ((unsigned)h) << 16;
    return v.f;
}

// ---- 1. prep: ligand center, sq, d_lig, packed hi/lo coords (+sq split); also zeroes pav ----
__global__ void __launch_bounds__(256) k_prep(const float* __restrict__ pos, const float* __restrict__ lig, int M,
                       unsigned short* __restrict__ pa, unsigned short* __restrict__ pb,
                       float* __restrict__ sq, float* __restrict__ dl, float* __restrict__ pav) {
    __shared__ float ls[128];
    __shared__ float ctr[3];
    int tid = threadIdx.x;
    if (blockIdx.x == 0 && tid < HIDDEN) pav[tid] = 0.f;
    for (int i = tid; i < 3 * M; i += 256) ls[i] = lig[i];
    __syncthreads();
    if (tid < 3) {
        float s = 0.f;
        for (int i = 0; i < M; i++) s += ls[i * 3 + tid];
        ctr[tid] = s / (float)M;
    }
    __syncthreads();
    int i = blockIdx.x * 256 + tid;
    float x = pos[i*3+0], y = pos[i*3+1], z = pos[i*3+2];
    float s = (x*x + y*y) + z*z;
    sq[i] = s;
    float dx = x - ctr[0], dy = y - ctr[1], dz = z - ctr[2];
    dl[i] = sqrtf((dx*dx + dy*dy) + dz*dz);
    unsigned short xh = f2bf(x); float xr = bf2f(xh); float xl = x - xr;
    unsigned short yh = f2bf(y); float yr = bf2f(yh); float yl = y - yr;
    unsigned short zh = f2bf(z); float zr = bf2f(zh); float zl = z - zr;
    unsigned short xlb = f2bf(xl), ylb = f2bf(yl), zlb = f2bf(zl);
    unsigned short xhA = f2bf(-2.f*xr), xlA = f2bf(-2.f*xl);
    unsigned short yhA = f2bf(-2.f*yr), ylA = f2bf(-2.f*yl);
    unsigned short zhA = f2bf(-2.f*zr), zlA = f2bf(-2.f*zl);
    unsigned short sih = f2bf(s);
    unsigned short sil = f2bf(s - bf2f(sih));
    unsigned short one = f2bf(1.0f);
    union { unsigned short s[16]; float4 f[2]; } A, B;
    // k-slots: per coord (hh, h*lo_j, lo_i*h), 9-11 lo*lo, 12-13 s_a*1, 14-15 1*s_b
    A.s[0]=xhA; A.s[1]=xhA; A.s[2]=xlA;
    A.s[3]=yhA; A.s[4]=yhA; A.s[5]=ylA;
    A.s[6]=zhA; A.s[7]=zhA; A.s[8]=zlA;
    A.s[9]=xlA; A.s[10]=ylA; A.s[11]=zlA;
    A.s[12]=sih; A.s[13]=sil; A.s[14]=one; A.s[15]=one;
    B.s[0]=xh;  B.s[1]=xlb;  B.s[2]=xh;
    B.s[3]=yh;  B.s[4]=ylb;  B.s[5]=yh;
    B.s[6]=zh;  B.s[7]=zlb;  B.s[8]=zh;
    B.s[9]=xlb; B.s[10]=ylb; B.s[11]=zlb;
    B.s[12]=one; B.s[13]=one; B.s[14]=sih; B.s[15]=sil;
    float4* pad = (float4*)(pa + (size_t)i * 16);
    pad[0] = A.f[0]; pad[1] = A.f[1];
    float4* pbd = (float4*)(pb + (size_t)i * 16);
    pbd[0] = B.f[0]; pbd[1] = B.f[1];
}

// ---- 2. neighbor counts via ONE 32x32x16 MFMA per 1024 pairs ----
// A = pa[j-tile] (LDS), B = pb[i-rows] (regs). C col=lane&31 -> i fixed per lane.
// grid (128, 16), block 256 = 4 waves x 32 i-rows; 1024 j per block
__global__ void __launch_bounds__(256) k_neighbor(
        const unsigned short* __restrict__ pa, const unsigned short* __restrict__ pb,
        int* __restrict__ cnt, unsigned int* __restrict__ flg, unsigned int* __restrict__ nflag) {
    __shared__ unsigned short js[256 * 24];     // 48B row stride (16B-aligned halves)
    __shared__ unsigned int fbuf[LCAP];
    __shared__ unsigned int fcnt, fbase;
    int tid = threadIdx.x;
    if (tid == 0) fcnt = 0;
    int lane = tid & 63, w = tid >> 6;
    int half = lane >> 5, il = lane & 31;
    int i = blockIdx.x * 128 + w * 32 + il;
    bf16x8 bfrag = *(const bf16x8*)(pb + (size_t)i * 16 + half * 8);
    int jb0 = blockIdx.y * 1024;
    int acc = 0;
    for (int chv = 0; chv < 4; chv++) {
        int jb = jb0 + chv * 256;
        __syncthreads();
        {
            const float4* src = (const float4*)(pa + (size_t)(jb + tid) * 16);
            float4 v0 = src[0], v1 = src[1];
            float4* dst = (float4*)&js[tid * 24];
            dst[0] = v0; dst[1] = v1;
        }
        __syncthreads();
        #pragma unroll 2
        for (int t = 0; t < 8; t++) {
            bf16x8 afrag = *(const bf16x8*)&js[(t * 32 + il) * 24 + half * 8];
            f32x16 c = {0.f,0.f,0.f,0.f,0.f,0.f,0.f,0.f,0.f,0.f,0.f,0.f,0.f,0.f,0.f,0.f};
            c = __builtin_amdgcn_mfma_f32_32x32x16_bf16(afrag, bfrag, c, 0, 0, 0);
            int cs = 0, cl = 0;
            #pragma unroll
            for (int r = 0; r < 16; r++) {
                cs += (c[r] < 9.0f - TAU);
                cl += (c[r] < 9.0f + TAU);
            }
            acc += cs;
            if (cl != cs) {                  // rare: boundary pair(s) in this lane's column
                int jt = jb + t * 32;
                #pragma unroll
                for (int r = 0; r < 16; r++) {
                    float d = c[r];
                    if (d < 9.0f + TAU && d >= 9.0f - TAU) {
                        int j = jt + (r & 3) + 8 * (r >> 2) + 4 * half;
                        unsigned xx = atomicAdd(&fcnt, 1u);
                        if (xx < LCAP) fbuf[xx] = ((unsigned)i << 14) | (unsigned)j;
                    }
                }
            }
        }
    }
    acc += __shfl_xor(acc, 32);
    if (half == 0) atomicAdd(&cnt[i], acc);
    __syncthreads();
    if (tid == 0) {
        unsigned cf = fcnt; if (cf > LCAP) cf = LCAP;
        fcnt = cf;
        fbase = atomicAdd(nflag, cf);
    }
    __syncthreads();
    unsigned cf = fcnt, fb = fbase;
    for (unsigned xx = tid; xx < cf; xx += 256) {
        unsigned di = fb + xx;
        if (di < FCAP) flg[di] = fbuf[xx];
    }
}

// ---- 2b. resolve boundary-window pairs exactly (fp32) ----
__global__ void __launch_bounds__(256) k_fixup(const float* __restrict__ pos, const float* __restrict__ sq,
        const unsigned int* __restrict__ flg, const unsigned int* __restrict__ nflag,
        int* __restrict__ cnt) {
    int nf = (int)*nflag; if (nf > FCAP) nf = FCAP;
    for (int idx = blockIdx.x * 256 + threadIdx.x; idx < nf; idx += gridDim.x * 256) {
        unsigned pr = flg[idx];
        int i = (int)((pr >> 14) & 16383u), j = (int)(pr & 16383u);
        float xi = pos[i*3+0], yi = pos[i*3+1], zi = pos[i*3+2];
        float xj = pos[j*3+0], yj = pos[j*3+1], zj = pos[j*3+2];
        float dot = fmaf(xi, xj, fmaf(yi, yj, zi * zj));
        float d2 = (sq[i] + sq[j]) - 2.0f * dot;
        if (d2 < 9.0f) atomicAdd(&cnt[i], 1);
    }
}

// ---- 3. scores (fused) + exact top-KSEL radix select (parallel suffix scan) ----
__global__ void __launch_bounds__(1024) k_select(const float* __restrict__ dl, const int* __restrict__ cnt,
                                                 int* __restrict__ sel) {
    __shared__ unsigned int sk[NPTS];
    __shared__ int hist[256];
    __shared__ int scan2[256];
    __shared__ unsigned int s_prefix;
    __shared__ int s_rem, s_eqtot, s_nout, s_digit, s_cgt;
    int tid = threadIdx.x;
    for (int i = tid; i < NPTS; i += 1024) {
        float score = 1.0f / (1.0f + dl[i] / 5.0f) + 0.5f * (1.0f / (float)cnt[i]);
        unsigned int u = __float_as_uint(score);
        sk[i] = u ^ ((u & 0x80000000u) ? 0xFFFFFFFFu : 0x80000000u);
    }
    if (tid == 0) { s_prefix = 0; s_rem = KSEL; s_nout = 0; s_eqtot = 0; }
    __syncthreads();
    for (int p = 0; p < 4; p++) {
        int sh = 24 - 8 * p;
        if (tid < 256) hist[tid] = 0;
        __syncthreads();
        unsigned int pref = s_prefix;
        int shp = (p == 0) ? 0 : (32 - 8 * p);
        for (int i = tid; i < NPTS; i += 1024) {
            unsigned int key = sk[i];
            bool m = (p == 0) || ((key >> shp) == pref);
            if (m) atomicAdd(&hist[(key >> sh) & 255], 1);
        }
        __syncthreads();
        if (tid < 256) scan2[tid] = hist[tid];
        __syncthreads();
        for (int off = 1; off < 256; off <<= 1) {
            int v = 0;
            if (tid < 256) { v = scan2[tid]; if (tid + off < 256) v += scan2[tid + off]; }
            __syncthreads();
            if (tid < 256) scan2[tid] = v;
            __syncthreads();
        }
        int rem = s_rem;
        if (tid < 256) {
            int hi = scan2[tid];
            int lo = hi - hist[tid];
            if (hi >= rem && lo < rem) { s_digit = tid; s_cgt = lo; }
        }
        __syncthreads();
        if (tid == 0) {
            s_prefix = (s_prefix << 8) | (unsigned int)s_digit;
            s_rem = rem - s_cgt;
            if (p == 3) s_eqtot = hist[s_digit];
        }
        __syncthreads();
    }
    unsigned int T = s_prefix;
    int need_eq = s_rem;
    for (int i = tid; i < NPTS; i += 1024)
        if (sk[i] > T) sel[atomicAdd(&s_nout, 1)] = i;
    __syncthreads();
    if (s_eqtot == need_eq) {
        for (int i = tid; i < NPTS; i += 1024)
            if (sk[i] == T) sel[atomicAdd(&s_nout, 1)] = i;
    } else {
        for (int i = tid; i < NPTS; i += 1024) {
            if (sk[i] == T) {
                int rank = 0;
                for (int j = 0; j < i; j++) rank += (sk[j] == T);
                if (rank < need_eq) sel[atomicAdd(&s_nout, 1)] = i;
            }
        }
    }
}

// ---- 4. gather + node embed + QKV projections (4 rows/block for 2 waves/SIMD) ----
__device__ __forceinline__ void proj4(const float hs[4][HIDDEN], const float* __restrict__ W,
                                      float b, int d, float* acc) {
    #pragma unroll
    for (int r = 0; r < 4; r++) acc[r] = b;
    for (int c = 0; c < HIDDEN; c += 4) {
        float w0 = W[(c+0)*HIDDEN+d], w1 = W[(c+1)*HIDDEN+d], w2 = W[(c+2)*HIDDEN+d], w3 = W[(c+3)*HIDDEN+d];
        #pragma unroll
        for (int r = 0; r < 4; r++) {
            float4 h4 = *(const float4*)&hs[r][c];
            float a = acc[r];
            a = fmaf(h4.x, w0, a); a = fmaf(h4.y, w1, a); a = fmaf(h4.z, w2, a); a = fmaf(h4.w, w3, a);
            acc[r] = a;
        }
    }
}

__global__ void __launch_bounds__(128) k_qkv(const float* __restrict__ x, const int* __restrict__ sel,
        const float* __restrict__ Wn, const float* __restrict__ bn,
        const float* __restrict__ Wq, const float* __restrict__ bq,
        const float* __restrict__ Wk, const float* __restrict__ bk,
        const float* __restrict__ Wv, const float* __restrict__ bv,
        unsigned short* __restrict__ qpk, unsigned short* __restrict__ kpk,
        float* __restrict__ vg) {
    __shared__ float xs[4][8];
    __shared__ __align__(16) float hs[4][HIDDEN];
    int d = threadIdx.x;
    int r0 = blockIdx.x * 4;
    if (d < 32) { int rr = d >> 3, cc = d & 7; xs[rr][cc] = x[(size_t)sel[r0 + rr] * 8 + cc]; }
    __syncthreads();
    {
        float wn[8];
        #pragma unroll
        for (int c = 0; c < 8; c++) wn[c] = Wn[c * HIDDEN + d];
        float b = bn[d];
        #pragma unroll
        for (int r = 0; r < 4; r++) {
            float a = b;
            #pragma unroll
            for (int c = 0; c < 8; c++) a = fmaf(xs[r][c], wn[c], a);
            hs[r][d] = a;
        }
    }
    __syncthreads();
    int hh = d >> 4, dd = d & 15;
    float acc[4];
    // Q (pre-scaled by log2(e)/4, split hi/lo)
    proj4(hs, Wq, bq[d], d, acc);
    #pragma unroll
    for (int r = 0; r < 4; r++) {
        float val = acc[r] * 0.36067376022224085f;
        unsigned short hi = f2bf(val);
        unsigned short lo = f2bf(val - bf2f(hi));
        size_t idx = ((size_t)(hh * KSEL) + r0 + r) * 32 + dd;
        qpk[idx] = hi; qpk[idx + 16] = lo;
    }
    // K
    proj4(hs, Wk, bk[d], d, acc);
    #pragma unroll
    for (int r = 0; r < 4; r++) {
        float val = acc[r];
        unsigned short hi = f2bf(val);
        unsigned short lo = f2bf(val - bf2f(hi));
        size_t idx = ((size_t)(hh * KSEL) + r0 + r) * 32 + dd;
        kpk[idx] = hi; kpk[idx + 16] = lo;
    }
    // V (fp32, row-major [q][128])
    proj4(hs, Wv, bv[d], d, acc);
    #pragma unroll
    for (int r = 0; r < 4; r++) vg[(size_t)(r0+r)*HIDDEN + d] = acc[r];
}

// ---- 5. phase 1: row sums l_q via MFMA; chunked LDS (256 rows, 80B stride) ----
__global__ void __launch_bounds__(256) k_attn_l(
        const unsigned short* __restrict__ qpk, const unsigned short* __restrict__ kpk,
        float* __restrict__ lp) {
    __shared__ unsigned short smem[256 * 40];
    int tid = threadIdx.x;
    int ks = blockIdx.x, yg = blockIdx.y, h = blockIdx.z;
    size_t hb = (size_t)h * KSEL;
    int lane = tid & 63, w = tid >> 6;
    int n = lane & 15, g = lane >> 4;
    int q0w = yg * 64 + w * 16;
    bf16x8 afrag = *(const bf16x8*)(qpk + (hb + q0w + n) * 32 + g * 8); // A=[Qh|Ql]
    float l0 = 0.f, l1 = 0.f, l2 = 0.f, l3 = 0.f;
    int b1off = (g & 1) * 8;
    int b2off = 16 + g * 8;
    for (int kc = 0; kc < 4; kc++) {
        __syncthreads();
        {
            int krow = ks * 1024 + kc * 256 + tid;
            const float4* src = (const float4*)(kpk + (hb + krow) * 32);
            float4 a0 = src[0], a1 = src[1], a2 = src[2], a3 = src[3];
            float4* dst = (float4*)&smem[tid * 40];
            dst[0] = a0; dst[1] = a1; dst[2] = a2; dst[3] = a3;
        }
        __syncthreads();
        #pragma unroll 4
        for (int t = 0; t < 16; t++) {
            const unsigned short* rowp = &smem[(t * 16 + n) * 40];
            bf16x8 b1 = *(const bf16x8*)(rowp + b1off);            // [Kh|Kh]
            bf16x8 b2 = {0,0,0,0,0,0,0,0};                          // [Kl|0]
            if (g < 2) b2 = *(const bf16x8*)(rowp + b2off);
            f32x4 c = {0.f, 0.f, 0.f, 0.f};
            c = __builtin_amdgcn_mfma_f32_16x16x32_bf16(afrag, b1, c, 0, 0, 0);
            c = __builtin_amdgcn_mfma_f32_16x16x32_bf16(afrag, b2, c, 0, 0, 0);
            l0 += E2(c[0]); l1 += E2(c[1]); l2 += E2(c[2]); l3 += E2(c[3]);
        }
    }
    #pragma unroll
    for (int m = 1; m < 16; m <<= 1) {
        l0 += __shfl_xor(l0, m); l1 += __shfl_xor(l1, m);
        l2 += __shfl_xor(l2, m); l3 += __shfl_xor(l3, m);
    }
    if (n == 0) {
        size_t base = (hb + q0w + g * 4) * NSLICE + ks;
        lp[base]            = l0; lp[base + NSLICE]     = l1;
        lp[base + 2*NSLICE] = l2; lp[base + 3*NSLICE]   = l3;
    }
}

// ---- 6. phase 2: column weights w_j = sum_q exp(s)/l_q (A = K-row [Kh|Kl]; 1/l inline) ----
__global__ void __launch_bounds__(256) k_attn_w(
        const unsigned short* __restrict__ qpk, const unsigned short* __restrict__ kpk,
        const float* __restrict__ lp, float* __restrict__ wp) {
    __shared__ unsigned short smem[256 * 40];
    __shared__ float rls[256];
    int tid = threadIdx.x;
    int qs = blockIdx.x, yg = blockIdx.y, h = blockIdx.z;
    size_t hb = (size_t)h * KSEL;
    int lane = tid & 63, w = tid >> 6;
    int n = lane & 15, g = lane >> 4;
    int j0w = yg * 64 + w * 16;
    bf16x8 afrag = *(const bf16x8*)(kpk + (hb + j0w + n) * 32 + g * 8); // A=[Kh|Kl]
    float w0 = 0.f, w1 = 0.f, w2 = 0.f, w3 = 0.f;
    int b1off = (g & 1) * 8;
    int b2off = 16 + g * 8;
    for (int qc = 0; qc < 4; qc++) {
        __syncthreads();
        {
            int qrow = qs * 1024 + qc * 256 + tid;
            const float4* src = (const float4*)(qpk + (hb + qrow) * 32);
            float4 a0 = src[0], a1 = src[1], a2 = src[2], a3 = src[3];
            float4* dst = (float4*)&smem[tid * 40];
            dst[0] = a0; dst[1] = a1; dst[2] = a2; dst[3] = a3;
            float4 p = ((const float4*)lp)[hb + qrow];
            rls[tid] = 1.0f / ((p.x + p.y) + (p.z + p.w));
        }
        __syncthreads();
        #pragma unroll 4
        for (int t = 0; t < 16; t++) {
            const unsigned short* rowp = &smem[(t * 16 + n) * 40];
            bf16x8 b1 = *(const bf16x8*)(rowp + b1off);            // [Qh|Qh]
            bf16x8 b2 = {0,0,0,0,0,0,0,0};                          // [Ql|0]
            if (g < 2) b2 = *(const bf16x8*)(rowp + b2off);
            f32x4 c = {0.f, 0.f, 0.f, 0.f};
            c = __builtin_amdgcn_mfma_f32_16x16x32_bf16(afrag, b1, c, 0, 0, 0);
            c = __builtin_amdgcn_mfma_f32_16x16x32_bf16(afrag, b2, c, 0, 0, 0);
            float rv = rls[t * 16 + n];
            w0 = fmaf(E2(c[0]), rv, w0); w1 = fmaf(E2(c[1]), rv, w1);
            w2 = fmaf(E2(c[2]), rv, w2); w3 = fmaf(E2(c[3]), rv, w3);
        }
    }
    #pragma unroll
    for (int m = 1; m < 16; m <<= 1) {
        w0 += __shfl_xor(w0, m); w1 += __shfl_xor(w1, m);
        w2 += __shfl_xor(w2, m); w3 += __shfl_xor(w3, m);
    }
    if (n == 0) {
        size_t base = (hb + j0w + g * 4) * NSLICE + qs;
        wp[base]            = w0; wp[base + NSLICE]     = w1;
        wp[base + 2*NSLICE] = w2; wp[base + 3*NSLICE]   = w3;
    }
}

// ---- 7. pooled_av[d] += (1/K) sum_j w[h(d)][j] * v[j][d]  (32 j per block) ----
__global__ void __launch_bounds__(256) k_colsum(const float* __restrict__ wp, const float* __restrict__ vg,
                                                float* __restrict__ pav) {
    __shared__ float wl[NHEADS][32];
    __shared__ float red[128];
    int tid = threadIdx.x;
    int j0 = blockIdx.x * 32;
    {
        int h = tid >> 5, jl = tid & 31;
        float4 p = ((const float4*)wp)[(size_t)h * KSEL + j0 + jl];
        wl[h][jl] = (p.x + p.y) + (p.z + p.w);
    }
    __syncthreads();
    int d = tid & 127, g = tid >> 7;
    int h = d >> 4;
    float acc = 0.f;
    for (int jl = g * 16; jl < g * 16 + 16; jl++)
        acc = fmaf(wl[h][jl], vg[(size_t)(j0 + jl) * HIDDEN + d], acc);
    if (g == 1) red[d] = acc;
    __syncthreads();
    if (g == 0) atomicAdd(&pav[d], (acc + red[d]) * (1.0f / (float)KSEL));
}

// ---- 8. out-proj + pool MLP ----
__global__ void __launch_bounds__(256) k_final(const float* __restrict__ pav,
        const float* __restrict__ Wo, const float* __restrict__ bo,
        const float* __restrict__ W1, const float* __restrict__ b1,
        const float* __restrict__ W2, const float* __restrict__ b2,
        float* __restrict__ out) {
    __shared__ float sp[HIDDEN];
    __shared__ float st[OUTD];
    int t = threadIdx.x;
    if (t < HIDDEN) {
        float a = bo[t];
        for (int c = 0; c < HIDDEN; c++) a = fmaf(pav[c], Wo[c * HIDDEN + t], a);
        sp[t] = a;
    }
    __syncthreads();
    {
        float a = b1[t];
        for (int c = 0; c < HIDDEN; c++) a = fmaf(sp[c], W1[c * OUTD + t], a);
        st[t] = fmaxf(a, 0.f);
    }
    __syncthreads();
    {
        float o = b2[t];
        for (int c = 0; c < OUTD; c++) o = fmaf(st[c], W2[c * OUTD + t], o);
        out[t] = o;
    }
}

extern "C" void kernel_launch(void* const* d_in, const int* in_sizes, int n_in,
                              void* d_out, int out_size, void* d_ws, size_t ws_size,
                              hipStream_t stream) {
    (void)n_in; (void)out_size; (void)ws_size;
    const float* x   = (const float*)d_in[0];
    const float* pos = (const float*)d_in[1];
    const float* lig = (const float*)d_in[2];
    const float* Wn  = (const float*)d_in[3];
    const float* bn  = (const float*)d_in[4];
    const float* Wq  = (const float*)d_in[5];
    const float* bq  = (const float*)d_in[6];
    const float* Wk  = (const float*)d_in[7];
    const float* bk  = (const float*)d_in[8];
    const float* Wv  = (const float*)d_in[9];
    const float* bv  = (const float*)d_in[10];
    const float* Wo  = (const float*)d_in[11];
    const float* bo  = (const float*)d_in[12];
    const float* W1  = (const float*)d_in[13];
    const float* b1  = (const float*)d_in[14];
    const float* W2  = (const float*)d_in[15];
    const float* b2  = (const float*)d_in[16];
    int M = in_sizes[2] / 3;

    char* ws = (char*)d_ws;
    unsigned short* pa  = (unsigned short*)(ws + OFF_PA);
    unsigned short* pb  = (unsigned short*)(ws + OFF_PB);
    float*          sq  = (float*)(ws + OFF_SQ);
    float*          dl  = (float*)(ws + OFF_DL);
    int*            cnt = (int*)  (ws + OFF_CNT);
    unsigned int*   nfl = (unsigned int*)(ws + OFF_NFLAG);
    unsigned int*   flg = (unsigned int*)(ws + OFF_FLG);
    int*            sel = (int*)  (ws + OFF_SEL);
    unsigned short* qpk = (unsigned short*)(ws + OFF_QPK);
    unsigned short* kpk = (unsigned short*)(ws + OFF_KPK);
    float*          vg  = (float*)(ws + OFF_V);
    float*          lp  = (float*)(ws + OFF_LP);
    float*          wp  = (float*)(ws + OFF_WP);
    float*          pav = (float*)(ws + OFF_PAV);

    hipMemsetAsync(ws + OFF_CNT, 0, (size_t)NPTS * 4 + 1024, stream);  // cnt + nflag

    hipLaunchKernelGGL(k_prep,     dim3(64),       dim3(256),  0, stream, pos, lig, M, pa, pb, sq, dl, pav);
    hipLaunchKernelGGL(k_neighbor, dim3(128, 16),  dim3(256),  0, stream, pa, pb, cnt, flg, nfl);
    hipLaunchKernelGGL(k_fixup,    dim3(32),       dim3(256),  0, stream, pos, sq, flg, nfl, cnt);
    hipLaunchKernelGGL(k_select,   dim3(1),        dim3(1024), 0, stream, dl, cnt, sel);
    hipLaunchKernelGGL(k_qkv,      dim3(KSEL/4),   dim3(128),  0, stream, x, sel, Wn, bn, Wq, bq, Wk, bk, Wv, bv, qpk, kpk, vg);
    hipLaunchKernelGGL(k_attn_l,   dim3(4, 64, 8), dim3(256),  0, stream, qpk, kpk, lp);
    hipLaunchKernelGGL(k_attn_w,   dim3(4, 64, 8), dim3(256),  0, stream, qpk, kpk, lp, wp);
    hipLaunchKernelGGL(k_colsum,   dim3(KSEL/32),  dim3(256),  0, stream, wp, vg, pav);
    hipLaunchKernelGGL(k_final,    dim3(1),        dim3(256),  0, stream, pav, Wo, bo, W1, b1, W2, b2, (float*)d_out);
}